// Round 9
// baseline (403.974 us; speedup 1.0000x reference)
//
#include <hip/hip_runtime.h>

// Problem constants (B=2, S=2048, HIDDEN=1024, HEADS=16, HEAD_DIM=64, ROT=16)
#define S_ 2048
#define EPSF 1e-8f
#define SCALEF 0.125f

typedef short bf16x8 __attribute__((ext_vector_type(8)));
typedef float f32x4 __attribute__((ext_vector_type(4)));

__device__ __forceinline__ unsigned short f2bf(float f){
  unsigned int u = __float_as_uint(f);
  u = (u + 0x7fffu + ((u >> 16) & 1u)) >> 16;
  return (unsigned short)u;
}
__device__ __forceinline__ float bf2f(unsigned short h){
  return __uint_as_float(((unsigned int)h) << 16);
}
__device__ __forceinline__ unsigned short f2bf_trunc(float f){
  return (unsigned short)(__float_as_uint(f) >> 16);
}

// ---------------- 1a: fp32 -> bf16 convert of hidden_states [4096][1024]
__global__ void k_conv_a(const float* __restrict__ A, unsigned short* __restrict__ Ab){
  int i = (blockIdx.x * 256 + threadIdx.x) * 4;   // exact fit: 4096 blocks
  float4 v = *(const float4*)(A + i);
  ushort4 o; o.x=f2bf(v.x); o.y=f2bf(v.y); o.z=f2bf(v.z); o.w=f2bf(v.w);
  *(ushort4*)(Ab + i) = o;
}

// ---------------- 1b: Wqkv cols [0,2048) -> WT bf16 [2048][1024] (transposed)
__global__ void k_conv_wt(const float* __restrict__ W, unsigned short* __restrict__ WT){
  __shared__ float t[32][33];
  int nt = blockIdx.x, kt = blockIdx.y;
  int tx = threadIdx.x & 31, ty = threadIdx.x >> 5;   // 32 x 8
  #pragma unroll
  for (int r = 0; r < 32; r += 8)
    t[ty + r][tx] = W[(size_t)(kt*32 + ty + r)*3072 + nt*32 + tx];
  __syncthreads();
  #pragma unroll
  for (int r = 0; r < 32; r += 8)
    WT[(size_t)(nt*32 + ty + r)*1024 + kt*32 + tx] = f2bf(t[tx][ty + r]);
}

// ---------------- 1c: v0[b,h,d] = hs[b,0,:] @ Wqkv[:, 2048+h*64+d] + bqkv
__global__ void k_v0(const float* __restrict__ hs, const float* __restrict__ Wqkv,
                     const float* __restrict__ bqkv, float* __restrict__ v0){
  int bh = blockIdx.x; int b = bh >> 4;
  int d = threadIdx.x & 63, kc = threadIdx.x >> 6;
  const float* x = hs + (size_t)b * S_ * 1024;
  int col = 2048 + (bh & 15)*64 + d;
  float acc = 0.f;
  #pragma unroll 8
  for (int k = kc*256; k < kc*256 + 256; ++k)
    acc = fmaf(x[k], Wqkv[(size_t)k*3072 + col], acc);
  __shared__ float red[4][64];
  red[kc][d] = acc;
  __syncthreads();
  if (kc == 0)
    v0[bh*64 + d] = red[0][d] + red[1][d] + red[2][d] + red[3][d] + bqkv[col];
}

// ---------------- 2: QK projection GEMM, M=4096 N=2048 K=1024, bf16 MFMA
#define GSTRIDE 72   // LDS row stride in bf16 elems
__launch_bounds__(256)
__global__ void k_gemm_qk(const unsigned short* __restrict__ Ab,
                          const unsigned short* __restrict__ WT,
                          const float* __restrict__ bqkv,
                          unsigned short* __restrict__ Qb,
                          unsigned short* __restrict__ Kb){
  __shared__ unsigned short At[128*GSTRIDE];
  __shared__ unsigned short Bt[128*GSTRIDE];
  const int m0 = blockIdx.y * 128, n0 = blockIdx.x * 128;
  const int w = threadIdx.x >> 6, l = threadIdx.x & 63;
  const int wr = w >> 1, wc = w & 1;
  f32x4 acc[4][4];
  #pragma unroll
  for (int i = 0; i < 4; ++i)
    #pragma unroll
    for (int j = 0; j < 4; ++j) acc[i][j] = (f32x4){0.f,0.f,0.f,0.f};

  const int srow = threadIdx.x >> 1;
  const int sseg = (threadIdx.x & 1) * 2;

  for (int kt = 0; kt < 1024; kt += 32){
    int4 va0 = *(const int4*)(Ab + (size_t)(m0+srow)*1024 + kt + sseg*8);
    int4 va1 = *(const int4*)(Ab + (size_t)(m0+srow)*1024 + kt + sseg*8 + 8);
    int4 vb0 = *(const int4*)(WT + (size_t)(n0+srow)*1024 + kt + sseg*8);
    int4 vb1 = *(const int4*)(WT + (size_t)(n0+srow)*1024 + kt + sseg*8 + 8);
    *(int4*)&At[srow*GSTRIDE + sseg*8]     = va0;
    *(int4*)&At[srow*GSTRIDE + sseg*8 + 8] = va1;
    *(int4*)&Bt[srow*GSTRIDE + sseg*8]     = vb0;
    *(int4*)&Bt[srow*GSTRIDE + sseg*8 + 8] = vb1;
    __syncthreads();
    bf16x8 af[4], bf[4];
    #pragma unroll
    for (int i = 0; i < 4; ++i)
      af[i] = *(const bf16x8*)&At[(wr*64 + i*16 + (l&15))*GSTRIDE + (l>>4)*8];
    #pragma unroll
    for (int j = 0; j < 4; ++j)
      bf[j] = *(const bf16x8*)&Bt[(wc*64 + j*16 + (l&15))*GSTRIDE + (l>>4)*8];
    #pragma unroll
    for (int i = 0; i < 4; ++i)
      #pragma unroll
      for (int j = 0; j < 4; ++j)
        acc[i][j] = __builtin_amdgcn_mfma_f32_16x16x32_bf16(af[i], bf[j], acc[i][j], 0, 0, 0);
    __syncthreads();
  }
  #pragma unroll
  for (int i = 0; i < 4; ++i){
    #pragma unroll
    for (int j = 0; j < 4; ++j){
      #pragma unroll
      for (int r = 0; r < 4; ++r){
        int m = m0 + wr*64 + i*16 + (l>>4)*4 + r;
        int n = n0 + wc*64 + j*16 + (l&15);
        float v = acc[i][j][r] + bqkv[n];
        int b = m >> 11, s = m & 2047;
        int tsel = n >> 10; int nq = n & 1023;
        int h = nq >> 6, d = nq & 63;
        unsigned short* dst = tsel ? Kb : Qb;
        dst[((size_t)(b*16 + h)*S_ + s)*64 + d] = f2bf(v);
      }
    }
  }
}

// ---------------- 3: RoPE in place on Q,K (first 16 dims per head row)
__global__ void k_rope(unsigned short* __restrict__ Qb, unsigned short* __restrict__ Kb,
                       const int* __restrict__ pos_ids){
  int idx = blockIdx.x * 256 + threadIdx.x;   // 2^20 total: t(1) bh(5) s(11) d(3)
  int d = idx & 7;
  int s = (idx >> 3) & 2047;
  int bh = (idx >> 14) & 31;
  int tsel = idx >> 19;
  unsigned short* X = tsel ? Kb : Qb;
  size_t base = ((size_t)bh * S_ + s) * 64;
  float pos = (float)pos_ids[s];
  float freq = exp2f(-1.6609640474436813f * (float)d);  // 10000^(-d/8)
  float th = pos * freq;
  float sn = __sinf(th), cn = __cosf(th);
  float x0 = bf2f(X[base + d]), x1 = bf2f(X[base + d + 8]);
  X[base + d]     = f2bf(x0 * cn - x1 * sn);
  X[base + d + 8] = f2bf(x1 * cn + x0 * sn);
}

// ---------------- 4a: full-chip E + rinv precompute.
// WG per (bi, bh). E tile (bi,bj) at Eg[(bh*528 + tri(bi)+bj)*4096],
// quarter-major [w][16 rows][64 cols]. rinv_i = 1/(D+eps(D+E_ii)).
#define KST2 66
__launch_bounds__(256, 4)
__global__ void k_scores(const unsigned short* __restrict__ Qb,
                         const unsigned short* __restrict__ Kb,
                         unsigned short* __restrict__ Eg,
                         float* __restrict__ rinvg){
  __shared__ unsigned short Ks[64*KST2];
  __shared__ float dsh[4][16];
  const int bi = blockIdx.x >> 5, bh = blockIdx.x & 31;
  const unsigned short* Qh = Qb + (size_t)bh * S_ * 64;
  const unsigned short* Kh = Kb + (size_t)bh * S_ * 64;
  const int tid = threadIdx.x, w = tid >> 6, l = tid & 63;
  const int lq = l & 15, lh = l >> 4;
  const unsigned short* qp = Qh + (size_t)(bi*64 + w*16 + lq)*64 + lh*8;
  bf16x8 qf0 = *(const bf16x8*)(qp);
  bf16x8 qf1 = *(const bf16x8*)(qp + 32);
  float dacc[4] = {0.f,0.f,0.f,0.f};
  unsigned short* Etile0 = Eg + ((size_t)bh*528 + (size_t)(bi*(bi+1)/2))*4096;

  for (int bj = 0; bj <= bi; ++bj){
    __syncthreads();
    {
      int srow = tid >> 2, sc = (tid & 3)*16;
      const unsigned short* src = Kh + (size_t)(bj*64 + srow)*64 + sc;
      *(int4*)&Ks[srow*KST2 + sc]     = *(const int4*)(src);
      *(int4*)&Ks[srow*KST2 + sc + 8] = *(const int4*)(src + 8);
    }
    __syncthreads();
    unsigned short* Et = Etile0 + (size_t)bj*4096 + w*1024;
    const bool diag = (bj == bi);
    #pragma unroll
    for (int ct = 0; ct < 4; ++ct){
      bf16x8 b0 = *(const bf16x8*)&Ks[(ct*16 + lq)*KST2 + lh*8];
      bf16x8 b1 = *(const bf16x8*)&Ks[(ct*16 + lq)*KST2 + 32 + lh*8];
      f32x4 a = (f32x4){0.f,0.f,0.f,0.f};
      a = __builtin_amdgcn_mfma_f32_16x16x32_bf16(qf0, b0, a, 0, 0, 0);
      a = __builtin_amdgcn_mfma_f32_16x16x32_bf16(qf1, b1, a, 0, 0, 0);
      #pragma unroll
      for (int r = 0; r < 4; ++r){
        float e = __expf(a[r] * SCALEF);
        unsigned short eb = f2bf_trunc(e);
        int rrow = lh*4 + r, col = ct*16 + lq;
        Et[rrow*64 + col] = eb;
        float ev = bf2f(eb);
        int grow = w*16 + rrow;                 // global row within 64-block
        if (!diag || col < grow) dacc[r] += ev;
        if (diag && col == grow) dsh[w][rrow] = ev;
      }
    }
  }
  __syncthreads();
  #pragma unroll
  for (int r = 0; r < 4; ++r){
    float d = dacc[r];
    #pragma unroll
    for (int mm = 1; mm < 16; mm <<= 1) d += __shfl_xor(d, mm);
    float dE = dsh[w][lh*4 + r];
    float den = fmaf(EPSF, d + dE, d);
    float rv = 1.0f / den;
    if (lq == 0)
      rinvg[(size_t)bh*S_ + bi*64 + w*16 + lh*4 + r] = rv;
  }
}

// ---------------- 4b: pipelined sequential recurrence. One WG (16 waves)/head.
// Iteration bj, Phase A (concurrent): wave0 solves block bj; waves 1-15 fold
// column bj-1 into rows >= bj+1 with ALL unit loads batch-issued upfront
// (one exposed latency); waves 4-7 pre-issue the urgent tile loads
// (col bj, row bj+1); wave 15 prefetches diag bj+1. Phase B: urgent fold.
// NOTE: __launch_bounds__(1024,1) — only 32 WGs exist, so occupancy cannot
// exceed 1 WG/CU; capping VGPRs (R7's (1024,4)) just caused scratch spill.
#define MAXU 8
__launch_bounds__(1024, 1)
__global__ void k_recur2(const unsigned short* __restrict__ Eg,
                         const float* __restrict__ rinvg,
                         float* __restrict__ c_g){
  __shared__ float Pa[S_];                 // running P per row
  __shared__ float rs[S_];                 // rinv preload
  __shared__ float cs[2][64];              // c double-buffer
  __shared__ unsigned short Dsh[2][4096];  // diag tile double-buffer (swizzled)
  const int bh = blockIdx.x;
  const unsigned short* Eh = Eg + (size_t)bh * 528 * 4096;
  const int tid = threadIdx.x, w = tid >> 6, l = tid & 63;
  const int lq = l & 15, lh = l >> 4;
  Pa[tid] = 0.f; Pa[tid + 1024] = 0.f;
  rs[tid] = rinvg[(size_t)bh*S_ + tid];
  rs[tid + 1024] = rinvg[(size_t)bh*S_ + tid + 1024];
  if (w == 15){   // prefetch diag tile (0,0), XOR-swizzled rows
    #pragma unroll
    for (int eb = 0; eb < 8; ++eb){
      int bofs = ((eb*64 + l)*16) ^ (((l>>3)&7)<<4);
      *(int4*)((char*)Dsh[0] + bofs) = *(const int4*)(Eh + l*64 + eb*8);
    }
  }
  __syncthreads();

  for (int bj = 0; bj < 32; ++bj){
    const int cur = bj & 1;

    // ---- Phase A ----
    // urgent pre-issue (waves 4-7): tile (bj+1, col bj), quarter w-4
    bf16x8 ug0, ug1;
    const bool hasU = (bj < 31) && (w >= 4) && (w < 8);
    if (hasU){
      int bn = bj + 1;
      const unsigned short* tp =
          Eh + ((size_t)(bn*(bn+1)/2) + bj)*4096 + (size_t)(w-4)*1024;
      ug0 = *(const bf16x8*)(tp + lq*64 + lh*8);
      ug1 = *(const bf16x8*)(tp + lq*64 + 32 + lh*8);
    }
    // wave 15: prefetch next diag tile
    if (w == 15 && bj < 31){
      int bn = bj + 1;
      const unsigned short* src = Eh + ((size_t)(bn*(bn+1)/2) + bn)*4096;
      #pragma unroll
      for (int eb = 0; eb < 8; ++eb){
        int bofs = ((eb*64 + l)*16) ^ (((l>>3)&7)<<4);
        *(int4*)((char*)Dsh[cur^1] + bofs) = *(const int4*)(src + l*64 + eb*8);
      }
    }
    // wave 0: solve block bj
    if (w == 0){
      const int rr = l;
      bf16x8 er[8];
      #pragma unroll
      for (int eb = 0; eb < 8; ++eb){
        int bofs = ((eb*64 + rr)*16) ^ (((rr>>3)&7)<<4);
        er[eb] = *(const bf16x8*)((const char*)Dsh[cur] + bofs);
      }
      float rinv = rs[bj*64 + rr];
      float Pl = Pa[bj*64 + rr];
      float cval = 0.f;
      #pragma unroll
      for (int eb = 0; eb < 8; ++eb){
        #pragma unroll
        for (int e = 0; e < 8; ++e){
          int r = eb*8 + e;
          float t = Pl * rinv;
          float cr = __uint_as_float(
              (unsigned)__builtin_amdgcn_readlane(__float_as_uint(t), r));
          if (bj == 0 && r == 0) cr = 1.0f;
          if (rr == r) cval = cr;
          float m = (rr > r) ? bf2f((unsigned short)er[eb][e]) : 0.f;
          Pl = fmaf(m, cr, Pl);
        }
      }
      cs[cur][rr] = cval;
      c_g[((size_t)(bh >> 4)*S_ + (bj*64 + rr))*16 + (bh & 15)] = cval;
    } else if (bj >= 1){
      // deferred fold of column bj-1 into rows >= bj+1 (waves 1..15),
      // batch-issued loads: one exposed latency for up to MAXU units.
      const int nu_d = (31 - bj) * 4;
      const int colj = bj - 1;
      bf16x8 dc0 = (bf16x8){0,0,0,0,0,0,0,0};
      bf16x8 dc1 = (bf16x8){0,0,0,0,0,0,0,0};
      if (lq == 0){
        #pragma unroll
        for (int e = 0; e < 8; ++e){
          dc0[e] = (short)f2bf(cs[cur^1][lh*8 + e]);
          dc1[e] = (short)f2bf(cs[cur^1][32 + lh*8 + e]);
        }
      }
      bf16x8 p0[MAXU], p1[MAXU];
      #pragma unroll
      for (int uu = 0; uu < MAXU; ++uu){
        int u = (w - 1) + uu*15;
        if (u < nu_d){
          int bi = bj + 1 + (u >> 2);
          const unsigned short* tp =
              Eh + ((size_t)(bi*(bi+1)/2) + colj)*4096 + (size_t)(u&3)*1024;
          p0[uu] = *(const bf16x8*)(tp + lq*64 + lh*8);
          p1[uu] = *(const bf16x8*)(tp + lq*64 + 32 + lh*8);
        }
      }
      #pragma unroll
      for (int uu = 0; uu < MAXU; ++uu){
        int u = (w - 1) + uu*15;
        if (u < nu_d){
          f32x4 o = (f32x4){0.f,0.f,0.f,0.f};
          o = __builtin_amdgcn_mfma_f32_16x16x32_bf16(p0[uu], dc0, o, 0, 0, 0);
          o = __builtin_amdgcn_mfma_f32_16x16x32_bf16(p1[uu], dc1, o, 0, 0, 0);
          if (lq == 0){
            int bi = bj + 1 + (u >> 2);
            float* base = Pa + bi*64 + (u&3)*16 + lh*4;
            float4 v = *(float4*)base;
            v.x += o[0]; v.y += o[1]; v.z += o[2]; v.w += o[3];
            *(float4*)base = v;
          }
        }
      }
    }
    __syncthreads();   // cs[cur] visible; deferred folds done

    // ---- Phase B: urgent fold (waves 4-7) ----
    if (hasU){
      bf16x8 c0f = (bf16x8){0,0,0,0,0,0,0,0};
      bf16x8 c1f = (bf16x8){0,0,0,0,0,0,0,0};
      if (lq == 0){
        #pragma unroll
        for (int e = 0; e < 8; ++e){
          c0f[e] = (short)f2bf(cs[cur][lh*8 + e]);
          c1f[e] = (short)f2bf(cs[cur][32 + lh*8 + e]);
        }
      }
      f32x4 o = (f32x4){0.f,0.f,0.f,0.f};
      o = __builtin_amdgcn_mfma_f32_16x16x32_bf16(ug0, c0f, o, 0, 0, 0);
      o = __builtin_amdgcn_mfma_f32_16x16x32_bf16(ug1, c1f, o, 0, 0, 0);
      if (lq == 0){
        float* base = Pa + (bj+1)*64 + (w-4)*16 + lh*4;
        float4 v = *(float4*)base;
        v.x += o[0]; v.y += o[1]; v.z += o[2]; v.w += o[3];
        *(float4*)base = v;
      }
    }
    __syncthreads();   // urgent fold + Dsh[cur^1] ready for next solve
  }
}

// ---------------- 5a: U[b,h,n] = sum_d v0[b,h,d] * Wd[h*64+d][n]
__global__ void k_u(const float* __restrict__ v0, const float* __restrict__ Wd,
                    float* __restrict__ U){
  int bh = blockIdx.x; int h = bh & 15;
  __shared__ float vsh[64];
  if (threadIdx.x < 64) vsh[threadIdx.x] = v0[bh*64 + threadIdx.x];
  __syncthreads();
  for (int n = threadIdx.x; n < 1024; n += 256){
    float acc = 0.f;
    #pragma unroll 8
    for (int d = 0; d < 64; ++d) acc = fmaf(vsh[d], Wd[(size_t)(h*64 + d)*1024 + n], acc);
    U[(size_t)bh*1024 + n] = acc;
  }
}

// ---------------- 5b: out[b,s,n] = bd[n] + sum_h c[b,s,h] * U[b,h,n]
__global__ void k_out(const float* __restrict__ c_g, const float* __restrict__ U,
                      const float* __restrict__ bd, float* __restrict__ out){
  int bs = blockIdx.x; int b = bs >> 11;
  __shared__ float ch[16];
  if (threadIdx.x < 16) ch[threadIdx.x] = c_g[(size_t)bs*16 + threadIdx.x];
  __syncthreads();
  int n = threadIdx.x * 4;
  float4 acc = *(const float4*)(bd + n);
  #pragma unroll
  for (int h = 0; h < 16; ++h){
    float cc = ch[h];
    float4 u = *(const float4*)(U + ((size_t)(b*16 + h))*1024 + n);
    acc.x = fmaf(cc, u.x, acc.x); acc.y = fmaf(cc, u.y, acc.y);
    acc.z = fmaf(cc, u.z, acc.z); acc.w = fmaf(cc, u.w, acc.w);
  }
  *(float4*)(out + (size_t)bs*1024 + n) = acc;
}

extern "C" void kernel_launch(void* const* d_in, const int* in_sizes, int n_in,
                              void* d_out, int out_size, void* d_ws, size_t ws_size,
                              hipStream_t stream) {
  const float* hs   = (const float*)d_in[0];   // [2][2048][1024]
  const int*   pos  = (const int*)d_in[1];     // [2048]
  const float* Wqkv = (const float*)d_in[2];   // [1024][3072]
  const float* bqkv = (const float*)d_in[3];   // [3072]
  const float* Wd   = (const float*)d_in[4];   // [1024][1024]
  const float* bd   = (const float*)d_in[5];   // [1024]
  float* out = (float*)d_out;

  // workspace layout
  char* ws = (char*)d_ws;
  unsigned short* Ab = (unsigned short*)(ws);                       // 8 MB
  unsigned short* WT = (unsigned short*)(ws + (8u<<20));            // 4 MB
  unsigned short* Qb = (unsigned short*)(ws + (12u<<20));           // 8 MB
  unsigned short* Kb = (unsigned short*)(ws + (20u<<20));           // 8 MB
  float* v0  = (float*)(ws + (28u<<20));                            // 8 KB
  float* c_g = (float*)(ws + (28u<<20) + (1u<<16));                 // 256 KB
  float* U   = (float*)(ws + (28u<<20) + (1u<<16) + (1u<<18));      // 128 KB
  float* rinvg = (float*)(ws + (28u<<20) + (1u<<19));               // 256 KB
  unsigned short* Eg = (unsigned short*)(ws + (29u<<20));           // 132 MB

  k_conv_a <<<4096, 256, 0, stream>>>(hs, Ab);
  k_conv_wt<<<dim3(64, 32), 256, 0, stream>>>(Wqkv, WT);
  k_v0     <<<32, 256, 0, stream>>>(hs, Wqkv, bqkv, v0);
  k_gemm_qk<<<dim3(16, 32), 256, 0, stream>>>(Ab, WT, bqkv, Qb, Kb);
  k_rope   <<<4096, 256, 0, stream>>>(Qb, Kb, pos);
  k_scores <<<1024, 256, 0, stream>>>(Qb, Kb, Eg, rinvg);
  k_recur2 <<<32, 1024, 0, stream>>>(Eg, rinvg, c_g);
  k_u      <<<32, 256, 0, stream>>>(v0, Wd, U);
  k_out    <<<4096, 256, 0, stream>>>(c_g, U, bd, out);
}

// Round 10
// 318.847 us; speedup vs baseline: 1.2670x; 1.2670x over previous
//
#include <hip/hip_runtime.h>

// Problem constants (B=2, S=2048, HIDDEN=1024, HEADS=16, HEAD_DIM=64, ROT=16)
#define S_ 2048
#define EPSF 1e-8f
#define SCALEF 0.125f

typedef short bf16x8 __attribute__((ext_vector_type(8)));
typedef float f32x4 __attribute__((ext_vector_type(4)));

__device__ __forceinline__ unsigned short f2bf(float f){
  unsigned int u = __float_as_uint(f);
  u = (u + 0x7fffu + ((u >> 16) & 1u)) >> 16;
  return (unsigned short)u;
}
__device__ __forceinline__ float bf2f(unsigned short h){
  return __uint_as_float(((unsigned int)h) << 16);
}
__device__ __forceinline__ unsigned short f2bf_trunc(float f){
  return (unsigned short)(__float_as_uint(f) >> 16);
}

// ---------------- 1a: fp32 -> bf16 convert of hidden_states [4096][1024]
__global__ void k_conv_a(const float* __restrict__ A, unsigned short* __restrict__ Ab){
  int i = (blockIdx.x * 256 + threadIdx.x) * 4;   // exact fit: 4096 blocks
  float4 v = *(const float4*)(A + i);
  ushort4 o; o.x=f2bf(v.x); o.y=f2bf(v.y); o.z=f2bf(v.z); o.w=f2bf(v.w);
  *(ushort4*)(Ab + i) = o;
}

// ---------------- 1b: Wqkv cols [0,2048) -> WT bf16 [2048][1024] (transposed)
__global__ void k_conv_wt(const float* __restrict__ W, unsigned short* __restrict__ WT){
  __shared__ float t[32][33];
  int nt = blockIdx.x, kt = blockIdx.y;
  int tx = threadIdx.x & 31, ty = threadIdx.x >> 5;   // 32 x 8
  #pragma unroll
  for (int r = 0; r < 32; r += 8)
    t[ty + r][tx] = W[(size_t)(kt*32 + ty + r)*3072 + nt*32 + tx];
  __syncthreads();
  #pragma unroll
  for (int r = 0; r < 32; r += 8)
    WT[(size_t)(nt*32 + ty + r)*1024 + kt*32 + tx] = f2bf(t[tx][ty + r]);
}

// ---------------- 1c: v0[b,h,d] = hs[b,0,:] @ Wqkv[:, 2048+h*64+d] + bqkv
__global__ void k_v0(const float* __restrict__ hs, const float* __restrict__ Wqkv,
                     const float* __restrict__ bqkv, float* __restrict__ v0){
  int bh = blockIdx.x; int b = bh >> 4;
  int d = threadIdx.x & 63, kc = threadIdx.x >> 6;
  const float* x = hs + (size_t)b * S_ * 1024;
  int col = 2048 + (bh & 15)*64 + d;
  float acc = 0.f;
  #pragma unroll 8
  for (int k = kc*256; k < kc*256 + 256; ++k)
    acc = fmaf(x[k], Wqkv[(size_t)k*3072 + col], acc);
  __shared__ float red[4][64];
  red[kc][d] = acc;
  __syncthreads();
  if (kc == 0)
    v0[bh*64 + d] = red[0][d] + red[1][d] + red[2][d] + red[3][d] + bqkv[col];
}

// ---------------- 2: QK projection GEMM, M=4096 N=2048 K=1024, bf16 MFMA
#define GSTRIDE 72   // LDS row stride in bf16 elems
__launch_bounds__(256)
__global__ void k_gemm_qk(const unsigned short* __restrict__ Ab,
                          const unsigned short* __restrict__ WT,
                          const float* __restrict__ bqkv,
                          unsigned short* __restrict__ Qb,
                          unsigned short* __restrict__ Kb){
  __shared__ unsigned short At[128*GSTRIDE];
  __shared__ unsigned short Bt[128*GSTRIDE];
  const int m0 = blockIdx.y * 128, n0 = blockIdx.x * 128;
  const int w = threadIdx.x >> 6, l = threadIdx.x & 63;
  const int wr = w >> 1, wc = w & 1;
  f32x4 acc[4][4];
  #pragma unroll
  for (int i = 0; i < 4; ++i)
    #pragma unroll
    for (int j = 0; j < 4; ++j) acc[i][j] = (f32x4){0.f,0.f,0.f,0.f};

  const int srow = threadIdx.x >> 1;
  const int sseg = (threadIdx.x & 1) * 2;

  for (int kt = 0; kt < 1024; kt += 32){
    int4 va0 = *(const int4*)(Ab + (size_t)(m0+srow)*1024 + kt + sseg*8);
    int4 va1 = *(const int4*)(Ab + (size_t)(m0+srow)*1024 + kt + sseg*8 + 8);
    int4 vb0 = *(const int4*)(WT + (size_t)(n0+srow)*1024 + kt + sseg*8);
    int4 vb1 = *(const int4*)(WT + (size_t)(n0+srow)*1024 + kt + sseg*8 + 8);
    *(int4*)&At[srow*GSTRIDE + sseg*8]     = va0;
    *(int4*)&At[srow*GSTRIDE + sseg*8 + 8] = va1;
    *(int4*)&Bt[srow*GSTRIDE + sseg*8]     = vb0;
    *(int4*)&Bt[srow*GSTRIDE + sseg*8 + 8] = vb1;
    __syncthreads();
    bf16x8 af[4], bf[4];
    #pragma unroll
    for (int i = 0; i < 4; ++i)
      af[i] = *(const bf16x8*)&At[(wr*64 + i*16 + (l&15))*GSTRIDE + (l>>4)*8];
    #pragma unroll
    for (int j = 0; j < 4; ++j)
      bf[j] = *(const bf16x8*)&Bt[(wc*64 + j*16 + (l&15))*GSTRIDE + (l>>4)*8];
    #pragma unroll
    for (int i = 0; i < 4; ++i)
      #pragma unroll
      for (int j = 0; j < 4; ++j)
        acc[i][j] = __builtin_amdgcn_mfma_f32_16x16x32_bf16(af[i], bf[j], acc[i][j], 0, 0, 0);
    __syncthreads();
  }
  #pragma unroll
  for (int i = 0; i < 4; ++i){
    #pragma unroll
    for (int j = 0; j < 4; ++j){
      #pragma unroll
      for (int r = 0; r < 4; ++r){
        int m = m0 + wr*64 + i*16 + (l>>4)*4 + r;
        int n = n0 + wc*64 + j*16 + (l&15);
        float v = acc[i][j][r] + bqkv[n];
        int b = m >> 11, s = m & 2047;
        int tsel = n >> 10; int nq = n & 1023;
        int h = nq >> 6, d = nq & 63;
        unsigned short* dst = tsel ? Kb : Qb;
        dst[((size_t)(b*16 + h)*S_ + s)*64 + d] = f2bf(v);
      }
    }
  }
}

// ---------------- 3: RoPE in place on Q,K (first 16 dims per head row)
__global__ void k_rope(unsigned short* __restrict__ Qb, unsigned short* __restrict__ Kb,
                       const int* __restrict__ pos_ids){
  int idx = blockIdx.x * 256 + threadIdx.x;   // 2^20 total: t(1) bh(5) s(11) d(3)
  int d = idx & 7;
  int s = (idx >> 3) & 2047;
  int bh = (idx >> 14) & 31;
  int tsel = idx >> 19;
  unsigned short* X = tsel ? Kb : Qb;
  size_t base = ((size_t)bh * S_ + s) * 64;
  float pos = (float)pos_ids[s];
  float freq = exp2f(-1.6609640474436813f * (float)d);  // 10000^(-d/8)
  float th = pos * freq;
  float sn = __sinf(th), cn = __cosf(th);
  float x0 = bf2f(X[base + d]), x1 = bf2f(X[base + d + 8]);
  X[base + d]     = f2bf(x0 * cn - x1 * sn);
  X[base + d + 8] = f2bf(x1 * cn + x0 * sn);
}

// ---------------- 4a: full-chip E + rinv precompute.
// WG per (bi, bh). E tile (bi,bj) at Eg[(bh*528 + tri(bi)+bj)*4096],
// quarter-major [w][16 rows][64 cols]. rinv_i = 1/(D+eps(D+E_ii)).
#define KST2 66
__launch_bounds__(256, 4)
__global__ void k_scores(const unsigned short* __restrict__ Qb,
                         const unsigned short* __restrict__ Kb,
                         unsigned short* __restrict__ Eg,
                         float* __restrict__ rinvg){
  __shared__ unsigned short Ks[64*KST2];
  __shared__ float dsh[4][16];
  const int bi = blockIdx.x >> 5, bh = blockIdx.x & 31;
  const unsigned short* Qh = Qb + (size_t)bh * S_ * 64;
  const unsigned short* Kh = Kb + (size_t)bh * S_ * 64;
  const int tid = threadIdx.x, w = tid >> 6, l = tid & 63;
  const int lq = l & 15, lh = l >> 4;
  const unsigned short* qp = Qh + (size_t)(bi*64 + w*16 + lq)*64 + lh*8;
  bf16x8 qf0 = *(const bf16x8*)(qp);
  bf16x8 qf1 = *(const bf16x8*)(qp + 32);
  float dacc[4] = {0.f,0.f,0.f,0.f};
  unsigned short* Etile0 = Eg + ((size_t)bh*528 + (size_t)(bi*(bi+1)/2))*4096;

  for (int bj = 0; bj <= bi; ++bj){
    __syncthreads();
    {
      int srow = tid >> 2, sc = (tid & 3)*16;
      const unsigned short* src = Kh + (size_t)(bj*64 + srow)*64 + sc;
      *(int4*)&Ks[srow*KST2 + sc]     = *(const int4*)(src);
      *(int4*)&Ks[srow*KST2 + sc + 8] = *(const int4*)(src + 8);
    }
    __syncthreads();
    unsigned short* Et = Etile0 + (size_t)bj*4096 + w*1024;
    const bool diag = (bj == bi);
    #pragma unroll
    for (int ct = 0; ct < 4; ++ct){
      bf16x8 b0 = *(const bf16x8*)&Ks[(ct*16 + lq)*KST2 + lh*8];
      bf16x8 b1 = *(const bf16x8*)&Ks[(ct*16 + lq)*KST2 + 32 + lh*8];
      f32x4 a = (f32x4){0.f,0.f,0.f,0.f};
      a = __builtin_amdgcn_mfma_f32_16x16x32_bf16(qf0, b0, a, 0, 0, 0);
      a = __builtin_amdgcn_mfma_f32_16x16x32_bf16(qf1, b1, a, 0, 0, 0);
      #pragma unroll
      for (int r = 0; r < 4; ++r){
        float e = __expf(a[r] * SCALEF);
        unsigned short eb = f2bf_trunc(e);
        int rrow = lh*4 + r, col = ct*16 + lq;
        Et[rrow*64 + col] = eb;
        float ev = bf2f(eb);
        int grow = w*16 + rrow;                 // global row within 64-block
        if (!diag || col < grow) dacc[r] += ev;
        if (diag && col == grow) dsh[w][rrow] = ev;
      }
    }
  }
  __syncthreads();
  #pragma unroll
  for (int r = 0; r < 4; ++r){
    float d = dacc[r];
    #pragma unroll
    for (int mm = 1; mm < 16; mm <<= 1) d += __shfl_xor(d, mm);
    float dE = dsh[w][lh*4 + r];
    float den = fmaf(EPSF, d + dE, d);
    float rv = 1.0f / den;
    if (lq == 0)
      rinvg[(size_t)bh*S_ + bi*64 + w*16 + lh*4 + r] = rv;
  }
}

// ---------------- 4b: pipelined sequential recurrence. One WG (16 waves)/head.
// Register-file math: per-SIMD VGPR pool = 512; 1024-thr WG = 4 waves/SIMD.
// Default allocator targets 2 WGs/CU (8 waves/SIMD) -> 64-VGPR cap -> spills
// (R7/R8: WRITE_SIZE 11.8MB). amdgpu_waves_per_eu(4,4) pins 1 WG/CU -> 128.
// Fold staging in two rounds of 4 units (32 VGPR live) -> ~2 exposed
// latencies per column step instead of ~7 serial (R6).
#define MAXU 8
__global__ __launch_bounds__(1024)
__attribute__((amdgpu_waves_per_eu(4, 4)))
void k_recur2(const unsigned short* __restrict__ Eg,
              const float* __restrict__ rinvg,
              float* __restrict__ c_g){
  __shared__ float Pa[S_];                 // running P per row
  __shared__ float rs[S_];                 // rinv preload
  __shared__ float cs[2][64];              // c double-buffer
  __shared__ unsigned short Dsh[2][4096];  // diag tile double-buffer (swizzled)
  const int bh = blockIdx.x;
  const unsigned short* Eh = Eg + (size_t)bh * 528 * 4096;
  const int tid = threadIdx.x, w = tid >> 6, l = tid & 63;
  const int lq = l & 15, lh = l >> 4;
  Pa[tid] = 0.f; Pa[tid + 1024] = 0.f;
  rs[tid] = rinvg[(size_t)bh*S_ + tid];
  rs[tid + 1024] = rinvg[(size_t)bh*S_ + tid + 1024];
  if (w == 15){   // prefetch diag tile (0,0), XOR-swizzled rows
    #pragma unroll
    for (int eb = 0; eb < 8; ++eb){
      int bofs = ((eb*64 + l)*16) ^ (((l>>3)&7)<<4);
      *(int4*)((char*)Dsh[0] + bofs) = *(const int4*)(Eh + l*64 + eb*8);
    }
  }
  __syncthreads();

  for (int bj = 0; bj < 32; ++bj){
    const int cur = bj & 1;

    // ---- Phase A ----
    // urgent pre-issue (waves 4-7): tile (bj+1, col bj), quarter w-4
    bf16x8 ug0, ug1;
    const bool hasU = (bj < 31) && (w >= 4) && (w < 8);
    if (hasU){
      int bn = bj + 1;
      const unsigned short* tp =
          Eh + ((size_t)(bn*(bn+1)/2) + bj)*4096 + (size_t)(w-4)*1024;
      ug0 = *(const bf16x8*)(tp + lq*64 + lh*8);
      ug1 = *(const bf16x8*)(tp + lq*64 + 32 + lh*8);
    }
    // wave 15: prefetch next diag tile
    if (w == 15 && bj < 31){
      int bn = bj + 1;
      const unsigned short* src = Eh + ((size_t)(bn*(bn+1)/2) + bn)*4096;
      #pragma unroll
      for (int eb = 0; eb < 8; ++eb){
        int bofs = ((eb*64 + l)*16) ^ (((l>>3)&7)<<4);
        *(int4*)((char*)Dsh[cur^1] + bofs) = *(const int4*)(src + l*64 + eb*8);
      }
    }
    // wave 0: solve block bj
    if (w == 0){
      const int rr = l;
      bf16x8 er[8];
      #pragma unroll
      for (int eb = 0; eb < 8; ++eb){
        int bofs = ((eb*64 + rr)*16) ^ (((rr>>3)&7)<<4);
        er[eb] = *(const bf16x8*)((const char*)Dsh[cur] + bofs);
      }
      float rinv = rs[bj*64 + rr];
      float Pl = Pa[bj*64 + rr];
      float cval = 0.f;
      #pragma unroll
      for (int eb = 0; eb < 8; ++eb){
        #pragma unroll
        for (int e = 0; e < 8; ++e){
          int r = eb*8 + e;
          float t = Pl * rinv;
          float cr = __uint_as_float(
              (unsigned)__builtin_amdgcn_readlane(__float_as_uint(t), r));
          if (bj == 0 && r == 0) cr = 1.0f;
          if (rr == r) cval = cr;
          float m = (rr > r) ? bf2f((unsigned short)er[eb][e]) : 0.f;
          Pl = fmaf(m, cr, Pl);
        }
      }
      cs[cur][rr] = cval;
      c_g[((size_t)(bh >> 4)*S_ + (bj*64 + rr))*16 + (bh & 15)] = cval;
    } else if (bj >= 1){
      // deferred fold of column bj-1 into rows >= bj+1 (waves 1..15),
      // two batch rounds of 4 units: 2 exposed latencies per column.
      const int nu_d = (31 - bj) * 4;
      const int colj = bj - 1;
      bf16x8 dc0 = (bf16x8){0,0,0,0,0,0,0,0};
      bf16x8 dc1 = (bf16x8){0,0,0,0,0,0,0,0};
      if (lq == 0){
        #pragma unroll
        for (int e = 0; e < 8; ++e){
          dc0[e] = (short)f2bf(cs[cur^1][lh*8 + e]);
          dc1[e] = (short)f2bf(cs[cur^1][32 + lh*8 + e]);
        }
      }
      #pragma unroll 1
      for (int rb = 0; rb < 2; ++rb){
        const int ub = (w - 1) + rb*60;   // (rb*4)*15
        if (ub >= nu_d) break;
        bf16x8 p0[4], p1[4];
        #pragma unroll
        for (int uu = 0; uu < 4; ++uu){
          int u = ub + uu*15;
          if (u < nu_d){
            int bi = bj + 1 + (u >> 2);
            const unsigned short* tp =
                Eh + ((size_t)(bi*(bi+1)/2) + colj)*4096 + (size_t)(u&3)*1024;
            p0[uu] = *(const bf16x8*)(tp + lq*64 + lh*8);
            p1[uu] = *(const bf16x8*)(tp + lq*64 + 32 + lh*8);
          }
        }
        #pragma unroll
        for (int uu = 0; uu < 4; ++uu){
          int u = ub + uu*15;
          if (u < nu_d){
            f32x4 o = (f32x4){0.f,0.f,0.f,0.f};
            o = __builtin_amdgcn_mfma_f32_16x16x32_bf16(p0[uu], dc0, o, 0, 0, 0);
            o = __builtin_amdgcn_mfma_f32_16x16x32_bf16(p1[uu], dc1, o, 0, 0, 0);
            if (lq == 0){
              int bi = bj + 1 + (u >> 2);
              float* base = Pa + bi*64 + (u&3)*16 + lh*4;
              float4 v = *(float4*)base;
              v.x += o[0]; v.y += o[1]; v.z += o[2]; v.w += o[3];
              *(float4*)base = v;
            }
          }
        }
      }
    }
    __syncthreads();   // cs[cur] visible; deferred folds done

    // ---- Phase B: urgent fold (waves 4-7) ----
    if (hasU){
      bf16x8 c0f = (bf16x8){0,0,0,0,0,0,0,0};
      bf16x8 c1f = (bf16x8){0,0,0,0,0,0,0,0};
      if (lq == 0){
        #pragma unroll
        for (int e = 0; e < 8; ++e){
          c0f[e] = (short)f2bf(cs[cur][lh*8 + e]);
          c1f[e] = (short)f2bf(cs[cur][32 + lh*8 + e]);
        }
      }
      f32x4 o = (f32x4){0.f,0.f,0.f,0.f};
      o = __builtin_amdgcn_mfma_f32_16x16x32_bf16(ug0, c0f, o, 0, 0, 0);
      o = __builtin_amdgcn_mfma_f32_16x16x32_bf16(ug1, c1f, o, 0, 0, 0);
      if (lq == 0){
        float* base = Pa + (bj+1)*64 + (w-4)*16 + lh*4;
        float4 v = *(float4*)base;
        v.x += o[0]; v.y += o[1]; v.z += o[2]; v.w += o[3];
        *(float4*)base = v;
      }
    }
    __syncthreads();   // urgent fold + Dsh[cur^1] ready for next solve
  }
}

// ---------------- 5a: U[b,h,n] = sum_d v0[b,h,d] * Wd[h*64+d][n]
__global__ void k_u(const float* __restrict__ v0, const float* __restrict__ Wd,
                    float* __restrict__ U){
  int bh = blockIdx.x; int h = bh & 15;
  __shared__ float vsh[64];
  if (threadIdx.x < 64) vsh[threadIdx.x] = v0[bh*64 + threadIdx.x];
  __syncthreads();
  for (int n = threadIdx.x; n < 1024; n += 256){
    float acc = 0.f;
    #pragma unroll 8
    for (int d = 0; d < 64; ++d) acc = fmaf(vsh[d], Wd[(size_t)(h*64 + d)*1024 + n], acc);
    U[(size_t)bh*1024 + n] = acc;
  }
}

// ---------------- 5b: out[b,s,n] = bd[n] + sum_h c[b,s,h] * U[b,h,n]
__global__ void k_out(const float* __restrict__ c_g, const float* __restrict__ U,
                      const float* __restrict__ bd, float* __restrict__ out){
  int bs = blockIdx.x; int b = bs >> 11;
  __shared__ float ch[16];
  if (threadIdx.x < 16) ch[threadIdx.x] = c_g[(size_t)bs*16 + threadIdx.x];
  __syncthreads();
  int n = threadIdx.x * 4;
  float4 acc = *(const float4*)(bd + n);
  #pragma unroll
  for (int h = 0; h < 16; ++h){
    float cc = ch[h];
    float4 u = *(const float4*)(U + ((size_t)(b*16 + h))*1024 + n);
    acc.x = fmaf(cc, u.x, acc.x); acc.y = fmaf(cc, u.y, acc.y);
    acc.z = fmaf(cc, u.z, acc.z); acc.w = fmaf(cc, u.w, acc.w);
  }
  *(float4*)(out + (size_t)bs*1024 + n) = acc;
}

extern "C" void kernel_launch(void* const* d_in, const int* in_sizes, int n_in,
                              void* d_out, int out_size, void* d_ws, size_t ws_size,
                              hipStream_t stream) {
  const float* hs   = (const float*)d_in[0];   // [2][2048][1024]
  const int*   pos  = (const int*)d_in[1];     // [2048]
  const float* Wqkv = (const float*)d_in[2];   // [1024][3072]
  const float* bqkv = (const float*)d_in[3];   // [3072]
  const float* Wd   = (const float*)d_in[4];   // [1024][1024]
  const float* bd   = (const float*)d_in[5];   // [1024]
  float* out = (float*)d_out;

  // workspace layout
  char* ws = (char*)d_ws;
  unsigned short* Ab = (unsigned short*)(ws);                       // 8 MB
  unsigned short* WT = (unsigned short*)(ws + (8u<<20));            // 4 MB
  unsigned short* Qb = (unsigned short*)(ws + (12u<<20));           // 8 MB
  unsigned short* Kb = (unsigned short*)(ws + (20u<<20));           // 8 MB
  float* v0  = (float*)(ws + (28u<<20));                            // 8 KB
  float* c_g = (float*)(ws + (28u<<20) + (1u<<16));                 // 256 KB
  float* U   = (float*)(ws + (28u<<20) + (1u<<16) + (1u<<18));      // 128 KB
  float* rinvg = (float*)(ws + (28u<<20) + (1u<<19));               // 256 KB
  unsigned short* Eg = (unsigned short*)(ws + (29u<<20));           // 132 MB

  k_conv_a <<<4096, 256, 0, stream>>>(hs, Ab);
  k_conv_wt<<<dim3(64, 32), 256, 0, stream>>>(Wqkv, WT);
  k_v0     <<<32, 256, 0, stream>>>(hs, Wqkv, bqkv, v0);
  k_gemm_qk<<<dim3(16, 32), 256, 0, stream>>>(Ab, WT, bqkv, Qb, Kb);
  k_rope   <<<4096, 256, 0, stream>>>(Qb, Kb, pos);
  k_scores <<<1024, 256, 0, stream>>>(Qb, Kb, Eg, rinvg);
  k_recur2 <<<32, 1024, 0, stream>>>(Eg, rinvg, c_g);
  k_u      <<<32, 256, 0, stream>>>(v0, Wd, U);
  k_out    <<<4096, 256, 0, stream>>>(c_g, U, bd, out);
}

// Round 11
// 227.977 us; speedup vs baseline: 1.7720x; 1.3986x over previous
//
#include <hip/hip_runtime.h>

// Problem constants (B=2, S=2048, HIDDEN=1024, HEADS=16, HEAD_DIM=64, ROT=16)
#define S_ 2048
#define EPSF 1e-8f
#define SCALEF 0.125f

typedef short bf16x8 __attribute__((ext_vector_type(8)));
typedef float f32x4 __attribute__((ext_vector_type(4)));

__device__ __forceinline__ unsigned short f2bf(float f){
  unsigned int u = __float_as_uint(f);
  u = (u + 0x7fffu + ((u >> 16) & 1u)) >> 16;
  return (unsigned short)u;
}
__device__ __forceinline__ float bf2f(unsigned short h){
  return __uint_as_float(((unsigned int)h) << 16);
}
__device__ __forceinline__ unsigned short f2bf_trunc(float f){
  return (unsigned short)(__float_as_uint(f) >> 16);
}

// ---------------- 1a: fp32 -> bf16 convert of hidden_states [4096][1024]
__global__ void k_conv_a(const float* __restrict__ A, unsigned short* __restrict__ Ab){
  int i = (blockIdx.x * 256 + threadIdx.x) * 4;   // exact fit: 4096 blocks
  float4 v = *(const float4*)(A + i);
  ushort4 o; o.x=f2bf(v.x); o.y=f2bf(v.y); o.z=f2bf(v.z); o.w=f2bf(v.w);
  *(ushort4*)(Ab + i) = o;
}

// ---------------- 1b: Wqkv cols [0,2048) -> WT bf16 [2048][1024] (transposed)
__global__ void k_conv_wt(const float* __restrict__ W, unsigned short* __restrict__ WT){
  __shared__ float t[32][33];
  int nt = blockIdx.x, kt = blockIdx.y;
  int tx = threadIdx.x & 31, ty = threadIdx.x >> 5;   // 32 x 8
  #pragma unroll
  for (int r = 0; r < 32; r += 8)
    t[ty + r][tx] = W[(size_t)(kt*32 + ty + r)*3072 + nt*32 + tx];
  __syncthreads();
  #pragma unroll
  for (int r = 0; r < 32; r += 8)
    WT[(size_t)(nt*32 + ty + r)*1024 + kt*32 + tx] = f2bf(t[tx][ty + r]);
}

// ---------------- 1c: v0[b,h,d] = hs[b,0,:] @ Wqkv[:, 2048+h*64+d] + bqkv
__global__ void k_v0(const float* __restrict__ hs, const float* __restrict__ Wqkv,
                     const float* __restrict__ bqkv, float* __restrict__ v0){
  int bh = blockIdx.x; int b = bh >> 4;
  int d = threadIdx.x & 63, kc = threadIdx.x >> 6;
  const float* x = hs + (size_t)b * S_ * 1024;
  int col = 2048 + (bh & 15)*64 + d;
  float acc = 0.f;
  #pragma unroll 8
  for (int k = kc*256; k < kc*256 + 256; ++k)
    acc = fmaf(x[k], Wqkv[(size_t)k*3072 + col], acc);
  __shared__ float red[4][64];
  red[kc][d] = acc;
  __syncthreads();
  if (kc == 0)
    v0[bh*64 + d] = red[0][d] + red[1][d] + red[2][d] + red[3][d] + bqkv[col];
}

// ---------------- 2: QK projection GEMM, M=4096 N=2048 K=1024, bf16 MFMA
#define GSTRIDE 72   // LDS row stride in bf16 elems
__launch_bounds__(256)
__global__ void k_gemm_qk(const unsigned short* __restrict__ Ab,
                          const unsigned short* __restrict__ WT,
                          const float* __restrict__ bqkv,
                          unsigned short* __restrict__ Qb,
                          unsigned short* __restrict__ Kb){
  __shared__ unsigned short At[128*GSTRIDE];
  __shared__ unsigned short Bt[128*GSTRIDE];
  const int m0 = blockIdx.y * 128, n0 = blockIdx.x * 128;
  const int w = threadIdx.x >> 6, l = threadIdx.x & 63;
  const int wr = w >> 1, wc = w & 1;
  f32x4 acc[4][4];
  #pragma unroll
  for (int i = 0; i < 4; ++i)
    #pragma unroll
    for (int j = 0; j < 4; ++j) acc[i][j] = (f32x4){0.f,0.f,0.f,0.f};

  const int srow = threadIdx.x >> 1;
  const int sseg = (threadIdx.x & 1) * 2;

  for (int kt = 0; kt < 1024; kt += 32){
    int4 va0 = *(const int4*)(Ab + (size_t)(m0+srow)*1024 + kt + sseg*8);
    int4 va1 = *(const int4*)(Ab + (size_t)(m0+srow)*1024 + kt + sseg*8 + 8);
    int4 vb0 = *(const int4*)(WT + (size_t)(n0+srow)*1024 + kt + sseg*8);
    int4 vb1 = *(const int4*)(WT + (size_t)(n0+srow)*1024 + kt + sseg*8 + 8);
    *(int4*)&At[srow*GSTRIDE + sseg*8]     = va0;
    *(int4*)&At[srow*GSTRIDE + sseg*8 + 8] = va1;
    *(int4*)&Bt[srow*GSTRIDE + sseg*8]     = vb0;
    *(int4*)&Bt[srow*GSTRIDE + sseg*8 + 8] = vb1;
    __syncthreads();
    bf16x8 af[4], bf[4];
    #pragma unroll
    for (int i = 0; i < 4; ++i)
      af[i] = *(const bf16x8*)&At[(wr*64 + i*16 + (l&15))*GSTRIDE + (l>>4)*8];
    #pragma unroll
    for (int j = 0; j < 4; ++j)
      bf[j] = *(const bf16x8*)&Bt[(wc*64 + j*16 + (l&15))*GSTRIDE + (l>>4)*8];
    #pragma unroll
    for (int i = 0; i < 4; ++i)
      #pragma unroll
      for (int j = 0; j < 4; ++j)
        acc[i][j] = __builtin_amdgcn_mfma_f32_16x16x32_bf16(af[i], bf[j], acc[i][j], 0, 0, 0);
    __syncthreads();
  }
  #pragma unroll
  for (int i = 0; i < 4; ++i){
    #pragma unroll
    for (int j = 0; j < 4; ++j){
      #pragma unroll
      for (int r = 0; r < 4; ++r){
        int m = m0 + wr*64 + i*16 + (l>>4)*4 + r;
        int n = n0 + wc*64 + j*16 + (l&15);
        float v = acc[i][j][r] + bqkv[n];
        int b = m >> 11, s = m & 2047;
        int tsel = n >> 10; int nq = n & 1023;
        int h = nq >> 6, d = nq & 63;
        unsigned short* dst = tsel ? Kb : Qb;
        dst[((size_t)(b*16 + h)*S_ + s)*64 + d] = f2bf(v);
      }
    }
  }
}

// ---------------- 3: RoPE in place on Q,K (first 16 dims per head row)
__global__ void k_rope(unsigned short* __restrict__ Qb, unsigned short* __restrict__ Kb,
                       const int* __restrict__ pos_ids){
  int idx = blockIdx.x * 256 + threadIdx.x;   // 2^20 total: t(1) bh(5) s(11) d(3)
  int d = idx & 7;
  int s = (idx >> 3) & 2047;
  int bh = (idx >> 14) & 31;
  int tsel = idx >> 19;
  unsigned short* X = tsel ? Kb : Qb;
  size_t base = ((size_t)bh * S_ + s) * 64;
  float pos = (float)pos_ids[s];
  float freq = exp2f(-1.6609640474436813f * (float)d);  // 10000^(-d/8)
  float th = pos * freq;
  float sn = __sinf(th), cn = __cosf(th);
  float x0 = bf2f(X[base + d]), x1 = bf2f(X[base + d + 8]);
  X[base + d]     = f2bf(x0 * cn - x1 * sn);
  X[base + d + 8] = f2bf(x1 * cn + x0 * sn);
}

// ---------------- 4a: full-chip E + rinv precompute.
// WG per (bi, bh). E tile (bi,bj) at Eg[(bh*528 + tri(bi)+bj)*4096],
// quarter-major [w][16 rows][64 cols]. rinv_i = 1/(D+eps(D+E_ii)).
#define KST2 66
__launch_bounds__(256, 4)
__global__ void k_scores(const unsigned short* __restrict__ Qb,
                         const unsigned short* __restrict__ Kb,
                         unsigned short* __restrict__ Eg,
                         float* __restrict__ rinvg){
  __shared__ unsigned short Ks[64*KST2];
  __shared__ float dsh[4][16];
  const int bi = blockIdx.x >> 5, bh = blockIdx.x & 31;
  const unsigned short* Qh = Qb + (size_t)bh * S_ * 64;
  const unsigned short* Kh = Kb + (size_t)bh * S_ * 64;
  const int tid = threadIdx.x, w = tid >> 6, l = tid & 63;
  const int lq = l & 15, lh = l >> 4;
  const unsigned short* qp = Qh + (size_t)(bi*64 + w*16 + lq)*64 + lh*8;
  bf16x8 qf0 = *(const bf16x8*)(qp);
  bf16x8 qf1 = *(const bf16x8*)(qp + 32);
  float dacc[4] = {0.f,0.f,0.f,0.f};
  unsigned short* Etile0 = Eg + ((size_t)bh*528 + (size_t)(bi*(bi+1)/2))*4096;

  for (int bj = 0; bj <= bi; ++bj){
    __syncthreads();
    {
      int srow = tid >> 2, sc = (tid & 3)*16;
      const unsigned short* src = Kh + (size_t)(bj*64 + srow)*64 + sc;
      *(int4*)&Ks[srow*KST2 + sc]     = *(const int4*)(src);
      *(int4*)&Ks[srow*KST2 + sc + 8] = *(const int4*)(src + 8);
    }
    __syncthreads();
    unsigned short* Et = Etile0 + (size_t)bj*4096 + w*1024;
    const bool diag = (bj == bi);
    #pragma unroll
    for (int ct = 0; ct < 4; ++ct){
      bf16x8 b0 = *(const bf16x8*)&Ks[(ct*16 + lq)*KST2 + lh*8];
      bf16x8 b1 = *(const bf16x8*)&Ks[(ct*16 + lq)*KST2 + 32 + lh*8];
      f32x4 a = (f32x4){0.f,0.f,0.f,0.f};
      a = __builtin_amdgcn_mfma_f32_16x16x32_bf16(qf0, b0, a, 0, 0, 0);
      a = __builtin_amdgcn_mfma_f32_16x16x32_bf16(qf1, b1, a, 0, 0, 0);
      #pragma unroll
      for (int r = 0; r < 4; ++r){
        float e = __expf(a[r] * SCALEF);
        unsigned short eb = f2bf_trunc(e);
        int rrow = lh*4 + r, col = ct*16 + lq;
        Et[rrow*64 + col] = eb;
        float ev = bf2f(eb);
        int grow = w*16 + rrow;                 // global row within 64-block
        if (!diag || col < grow) dacc[r] += ev;
        if (diag && col == grow) dsh[w][rrow] = ev;
      }
    }
  }
  __syncthreads();
  #pragma unroll
  for (int r = 0; r < 4; ++r){
    float d = dacc[r];
    #pragma unroll
    for (int mm = 1; mm < 16; mm <<= 1) d += __shfl_xor(d, mm);
    float dE = dsh[w][lh*4 + r];
    float den = fmaf(EPSF, d + dE, d);
    float rv = 1.0f / den;
    if (lq == 0)
      rinvg[(size_t)bh*S_ + bi*64 + w*16 + lh*4 + r] = rv;
  }
}

// ---------------- 4b: striped recurrence, 4 WGs per head (128 WGs, 512 thr).
// blockIdx = s*32 + bh  => all 4 stripes of a head share one XCD (blk%8 == bh%8).
// Stripe s owns row-blocks {s, s+4, ..., s+28}. Owner of column bj solves it
// (diag tile in regs, pre-issued 4 columns early) and publishes c via
// agent-scope stores to c_c; other stripes POLL THE DATA (c>0 always; 0 =
// not-ready, c_c zeroed pre-launch). Fold loads pre-issued before the poll.
// Deps point strictly backward in bj and 128 WGs are co-resident: no deadlock.
__global__ __launch_bounds__(512)
__attribute__((amdgpu_waves_per_eu(2, 2)))   // VGPR budget 256: no spill
void k_recur3(const unsigned short* __restrict__ Eg,
              const float* __restrict__ rinvg,
              float* __restrict__ c_c,
              float* __restrict__ c_g){
  __shared__ float Pa[512];     // running P, owned blocks o=0..7 at Pa[o*64+row]
  __shared__ float rso[512];    // rinv for owned rows
  __shared__ float csl[64];     // current column's c
  const int bh = blockIdx.x & 31, s = blockIdx.x >> 5;
  const unsigned short* Eh = Eg + (size_t)bh * 528 * 4096;
  const int tid = threadIdx.x, w = tid >> 6, l = tid & 63;
  const int lq = l & 15, lh = l >> 4;

  Pa[tid] = 0.f;
  rso[tid] = rinvg[(size_t)bh*S_ + (s + 4*(tid >> 6))*64 + l];
  __syncthreads();

  // wave 0: diag tile of first owned block (s) into registers
  bf16x8 er[8];
  if (w == 0){
    const unsigned short* dt = Eh + ((size_t)(s*(s+1)/2) + s)*4096 + l*64;
    #pragma unroll
    for (int eb = 0; eb < 8; ++eb) er[eb] = *(const bf16x8*)(dt + eb*8);
  }

  const int lastc = s + 28;
  for (int bj = 0; bj <= lastc; ++bj){
    const bool own = ((bj & 3) == s);
    const int o0 = (bj >= s) ? (((bj - s) >> 2) + 1) : 0;  // first owned blk > bj
    const int nu = (8 - o0) * 4;                           // fold quarter-units

    // pre-issue fold loads (waves 1..7) — addresses independent of c
    bf16x8 p0[5], p1[5];
    if (w >= 1){
      #pragma unroll
      for (int k = 0; k < 5; ++k){
        int t = (w - 1) + k*7;
        if (t < nu){
          int bi = s + 4*(o0 + (t >> 2));
          const unsigned short* tp =
              Eh + ((size_t)(bi*(bi+1)/2) + bj)*4096 + (size_t)(t & 3)*1024;
          p0[k] = *(const bf16x8*)(tp + lq*64 + lh*8);
          p1[k] = *(const bf16x8*)(tp + lq*64 + 32 + lh*8);
        }
      }
    }

    if (own){
      if (w == 0){
        const int rr = l;
        float rinv = rso[((bj - s) >> 2)*64 + rr];
        float Pl = Pa[((bj - s) >> 2)*64 + rr];
        float cval = 0.f;
        #pragma unroll
        for (int eb = 0; eb < 8; ++eb){
          #pragma unroll
          for (int e = 0; e < 8; ++e){
            int r = eb*8 + e;
            float t2 = Pl * rinv;
            float cr = __uint_as_float(
                (unsigned)__builtin_amdgcn_readlane(__float_as_uint(t2), r));
            if (bj == 0 && r == 0) cr = 1.0f;
            if (rr == r) cval = cr;
            float m = (rr > r) ? bf2f((unsigned short)er[eb][e]) : 0.f;
            Pl = fmaf(m, cr, Pl);
          }
        }
        csl[rr] = cval;
        c_g[((size_t)(bh >> 4)*S_ + (bj*64 + rr))*16 + (bh & 15)] = cval;
        __hip_atomic_store((unsigned*)(c_c + (size_t)bh*S_ + bj*64 + rr),
                           __float_as_uint(cval),
                           __ATOMIC_RELAXED, __HIP_MEMORY_SCOPE_AGENT);
        // pre-issue next owned diag tile (bj+4) — 4 columns of lead time
        int bn = bj + 4;
        if (bn <= 31){
          const unsigned short* dt =
              Eh + ((size_t)(bn*(bn+1)/2) + bn)*4096 + l*64;
          #pragma unroll
          for (int eb = 0; eb < 8; ++eb) er[eb] = *(const bf16x8*)(dt + eb*8);
        }
      }
    } else {
      if (w == 0){
        const unsigned* pp = (const unsigned*)(c_c + (size_t)bh*S_ + bj*64 + l);
        unsigned v = __hip_atomic_load(pp, __ATOMIC_RELAXED,
                                       __HIP_MEMORY_SCOPE_AGENT);
        while (!__all(v != 0u)){
          __builtin_amdgcn_s_sleep(8);
          v = __hip_atomic_load(pp, __ATOMIC_RELAXED,
                                __HIP_MEMORY_SCOPE_AGENT);
        }
        csl[l] = __uint_as_float(v);
      }
    }
    __syncthreads();   // csl visible; Pa from prev folds stable

    // fold column bj into owned blocks > bj
    if (w >= 1 && nu > 0){
      bf16x8 dc0 = (bf16x8){0,0,0,0,0,0,0,0};
      bf16x8 dc1 = (bf16x8){0,0,0,0,0,0,0,0};
      if (lq == 0){
        #pragma unroll
        for (int e = 0; e < 8; ++e){
          dc0[e] = (short)f2bf(csl[lh*8 + e]);
          dc1[e] = (short)f2bf(csl[32 + lh*8 + e]);
        }
      }
      #pragma unroll
      for (int k = 0; k < 5; ++k){
        int t = (w - 1) + k*7;
        if (t < nu){
          f32x4 o = (f32x4){0.f,0.f,0.f,0.f};
          o = __builtin_amdgcn_mfma_f32_16x16x32_bf16(p0[k], dc0, o, 0, 0, 0);
          o = __builtin_amdgcn_mfma_f32_16x16x32_bf16(p1[k], dc1, o, 0, 0, 0);
          if (lq == 0){
            int ob = o0 + (t >> 2), qt = t & 3;
            float* base = Pa + ob*64 + qt*16 + lh*4;
            float4 v = *(float4*)base;
            v.x += o[0]; v.y += o[1]; v.z += o[2]; v.w += o[3];
            *(float4*)base = v;
          }
        }
      }
    }
    __syncthreads();   // folds done before next csl overwrite / solve
  }
}

// ---------------- 5a: U[b,h,n] = sum_d v0[b,h,d] * Wd[h*64+d][n]
__global__ void k_u(const float* __restrict__ v0, const float* __restrict__ Wd,
                    float* __restrict__ U){
  int bh = blockIdx.x; int h = bh & 15;
  __shared__ float vsh[64];
  if (threadIdx.x < 64) vsh[threadIdx.x] = v0[bh*64 + threadIdx.x];
  __syncthreads();
  for (int n = threadIdx.x; n < 1024; n += 256){
    float acc = 0.f;
    #pragma unroll 8
    for (int d = 0; d < 64; ++d) acc = fmaf(vsh[d], Wd[(size_t)(h*64 + d)*1024 + n], acc);
    U[(size_t)bh*1024 + n] = acc;
  }
}

// ---------------- 5b: out[b,s,n] = bd[n] + sum_h c[b,s,h] * U[b,h,n]
__global__ void k_out(const float* __restrict__ c_g, const float* __restrict__ U,
                      const float* __restrict__ bd, float* __restrict__ out){
  int bs = blockIdx.x; int b = bs >> 11;
  __shared__ float ch[16];
  if (threadIdx.x < 16) ch[threadIdx.x] = c_g[(size_t)bs*16 + threadIdx.x];
  __syncthreads();
  int n = threadIdx.x * 4;
  float4 acc = *(const float4*)(bd + n);
  #pragma unroll
  for (int h = 0; h < 16; ++h){
    float cc = ch[h];
    float4 u = *(const float4*)(U + ((size_t)(b*16 + h))*1024 + n);
    acc.x = fmaf(cc, u.x, acc.x); acc.y = fmaf(cc, u.y, acc.y);
    acc.z = fmaf(cc, u.z, acc.z); acc.w = fmaf(cc, u.w, acc.w);
  }
  *(float4*)(out + (size_t)bs*1024 + n) = acc;
}

extern "C" void kernel_launch(void* const* d_in, const int* in_sizes, int n_in,
                              void* d_out, int out_size, void* d_ws, size_t ws_size,
                              hipStream_t stream) {
  const float* hs   = (const float*)d_in[0];   // [2][2048][1024]
  const int*   pos  = (const int*)d_in[1];     // [2048]
  const float* Wqkv = (const float*)d_in[2];   // [1024][3072]
  const float* bqkv = (const float*)d_in[3];   // [3072]
  const float* Wd   = (const float*)d_in[4];   // [1024][1024]
  const float* bd   = (const float*)d_in[5];   // [1024]
  float* out = (float*)d_out;

  // workspace layout
  char* ws = (char*)d_ws;
  unsigned short* Ab = (unsigned short*)(ws);                       // 8 MB
  unsigned short* WT = (unsigned short*)(ws + (8u<<20));            // 4 MB
  unsigned short* Qb = (unsigned short*)(ws + (12u<<20));           // 8 MB
  unsigned short* Kb = (unsigned short*)(ws + (20u<<20));           // 8 MB
  float* v0   = (float*)(ws + (28u<<20));                           // 8 KB
  float* c_g  = (float*)(ws + (28u<<20) + 0x10000);                 // 256 KB
  float* U    = (float*)(ws + (28u<<20) + 0x50000);                 // 128 KB
  float* rinvg= (float*)(ws + (28u<<20) + 0x80000);                 // 256 KB
  float* c_c  = (float*)(ws + (28u<<20) + 0xC0000);                 // 256 KB
  unsigned short* Eg = (unsigned short*)(ws + (29u<<20));           // 132 MB

  k_conv_a <<<4096, 256, 0, stream>>>(hs, Ab);
  k_conv_wt<<<dim3(64, 32), 256, 0, stream>>>(Wqkv, WT);
  k_v0     <<<32, 256, 0, stream>>>(hs, Wqkv, bqkv, v0);
  k_gemm_qk<<<dim3(16, 32), 256, 0, stream>>>(Ab, WT, bqkv, Qb, Kb);
  k_rope   <<<4096, 256, 0, stream>>>(Qb, Kb, pos);
  k_scores <<<1024, 256, 0, stream>>>(Qb, Kb, Eg, rinvg);
  hipMemsetAsync(c_c, 0, 32 * S_ * sizeof(float), stream);
  k_recur3 <<<128, 512, 0, stream>>>(Eg, rinvg, c_c, c_g);
  k_u      <<<32, 256, 0, stream>>>(v0, Wd, U);
  k_out    <<<4096, 256, 0, stream>>>(c_g, U, bd, out);
}

// Round 13
// 218.648 us; speedup vs baseline: 1.8476x; 1.0427x over previous
//
#include <hip/hip_runtime.h>

// Problem constants (B=2, S=2048, HIDDEN=1024, HEADS=16, HEAD_DIM=64, ROT=16)
#define S_ 2048
#define EPSF 1e-8f
#define SCALEF 0.125f

typedef short bf16x8 __attribute__((ext_vector_type(8)));
typedef float f32x4 __attribute__((ext_vector_type(4)));

__device__ __forceinline__ unsigned short f2bf(float f){
  unsigned int u = __float_as_uint(f);
  u = (u + 0x7fffu + ((u >> 16) & 1u)) >> 16;
  return (unsigned short)u;
}
__device__ __forceinline__ float bf2f(unsigned short h){
  return __uint_as_float(((unsigned int)h) << 16);
}
__device__ __forceinline__ unsigned short f2bf_trunc(float f){
  return (unsigned short)(__float_as_uint(f) >> 16);
}

// ---------------- 1a: fp32 -> bf16 convert of hidden_states [4096][1024]
__global__ void k_conv_a(const float* __restrict__ A, unsigned short* __restrict__ Ab){
  int i = (blockIdx.x * 256 + threadIdx.x) * 4;   // exact fit: 4096 blocks
  float4 v = *(const float4*)(A + i);
  ushort4 o; o.x=f2bf(v.x); o.y=f2bf(v.y); o.z=f2bf(v.z); o.w=f2bf(v.w);
  *(ushort4*)(Ab + i) = o;
}

// ---------------- 1b: Wqkv cols [0,2048) -> WT bf16 [2048][1024] (transposed)
__global__ void k_conv_wt(const float* __restrict__ W, unsigned short* __restrict__ WT){
  __shared__ float t[32][33];
  int nt = blockIdx.x, kt = blockIdx.y;
  int tx = threadIdx.x & 31, ty = threadIdx.x >> 5;   // 32 x 8
  #pragma unroll
  for (int r = 0; r < 32; r += 8)
    t[ty + r][tx] = W[(size_t)(kt*32 + ty + r)*3072 + nt*32 + tx];
  __syncthreads();
  #pragma unroll
  for (int r = 0; r < 32; r += 8)
    WT[(size_t)(nt*32 + ty + r)*1024 + kt*32 + tx] = f2bf(t[tx][ty + r]);
}

// ---------------- 1c: v0[b,h,d] = hs[b,0,:] @ Wqkv[:, 2048+h*64+d] + bqkv
__global__ void k_v0(const float* __restrict__ hs, const float* __restrict__ Wqkv,
                     const float* __restrict__ bqkv, float* __restrict__ v0){
  int bh = blockIdx.x; int b = bh >> 4;
  int d = threadIdx.x & 63, kc = threadIdx.x >> 6;
  const float* x = hs + (size_t)b * S_ * 1024;
  int col = 2048 + (bh & 15)*64 + d;
  float acc = 0.f;
  #pragma unroll 8
  for (int k = kc*256; k < kc*256 + 256; ++k)
    acc = fmaf(x[k], Wqkv[(size_t)k*3072 + col], acc);
  __shared__ float red[4][64];
  red[kc][d] = acc;
  __syncthreads();
  if (kc == 0)
    v0[bh*64 + d] = red[0][d] + red[1][d] + red[2][d] + red[3][d] + bqkv[col];
}

// ---------------- 2: QK projection GEMM, M=4096 N=2048 K=1024, bf16 MFMA
#define GSTRIDE 72   // LDS row stride in bf16 elems
__launch_bounds__(256)
__global__ void k_gemm_qk(const unsigned short* __restrict__ Ab,
                          const unsigned short* __restrict__ WT,
                          const float* __restrict__ bqkv,
                          unsigned short* __restrict__ Qb,
                          unsigned short* __restrict__ Kb){
  __shared__ unsigned short At[128*GSTRIDE];
  __shared__ unsigned short Bt[128*GSTRIDE];
  const int m0 = blockIdx.y * 128, n0 = blockIdx.x * 128;
  const int w = threadIdx.x >> 6, l = threadIdx.x & 63;
  const int wr = w >> 1, wc = w & 1;
  f32x4 acc[4][4];
  #pragma unroll
  for (int i = 0; i < 4; ++i)
    #pragma unroll
    for (int j = 0; j < 4; ++j) acc[i][j] = (f32x4){0.f,0.f,0.f,0.f};

  const int srow = threadIdx.x >> 1;
  const int sseg = (threadIdx.x & 1) * 2;

  for (int kt = 0; kt < 1024; kt += 32){
    int4 va0 = *(const int4*)(Ab + (size_t)(m0+srow)*1024 + kt + sseg*8);
    int4 va1 = *(const int4*)(Ab + (size_t)(m0+srow)*1024 + kt + sseg*8 + 8);
    int4 vb0 = *(const int4*)(WT + (size_t)(n0+srow)*1024 + kt + sseg*8);
    int4 vb1 = *(const int4*)(WT + (size_t)(n0+srow)*1024 + kt + sseg*8 + 8);
    *(int4*)&At[srow*GSTRIDE + sseg*8]     = va0;
    *(int4*)&At[srow*GSTRIDE + sseg*8 + 8] = va1;
    *(int4*)&Bt[srow*GSTRIDE + sseg*8]     = vb0;
    *(int4*)&Bt[srow*GSTRIDE + sseg*8 + 8] = vb1;
    __syncthreads();
    bf16x8 af[4], bf[4];
    #pragma unroll
    for (int i = 0; i < 4; ++i)
      af[i] = *(const bf16x8*)&At[(wr*64 + i*16 + (l&15))*GSTRIDE + (l>>4)*8];
    #pragma unroll
    for (int j = 0; j < 4; ++j)
      bf[j] = *(const bf16x8*)&Bt[(wc*64 + j*16 + (l&15))*GSTRIDE + (l>>4)*8];
    #pragma unroll
    for (int i = 0; i < 4; ++i)
      #pragma unroll
      for (int j = 0; j < 4; ++j)
        acc[i][j] = __builtin_amdgcn_mfma_f32_16x16x32_bf16(af[i], bf[j], acc[i][j], 0, 0, 0);
    __syncthreads();
  }
  #pragma unroll
  for (int i = 0; i < 4; ++i){
    #pragma unroll
    for (int j = 0; j < 4; ++j){
      #pragma unroll
      for (int r = 0; r < 4; ++r){
        int m = m0 + wr*64 + i*16 + (l>>4)*4 + r;
        int n = n0 + wc*64 + j*16 + (l&15);
        float v = acc[i][j][r] + bqkv[n];
        int b = m >> 11, s = m & 2047;
        int tsel = n >> 10; int nq = n & 1023;
        int h = nq >> 6, d = nq & 63;
        unsigned short* dst = tsel ? Kb : Qb;
        dst[((size_t)(b*16 + h)*S_ + s)*64 + d] = f2bf(v);
      }
    }
  }
}

// ---------------- 3: RoPE in place on Q,K (first 16 dims per head row)
__global__ void k_rope(unsigned short* __restrict__ Qb, unsigned short* __restrict__ Kb,
                       const int* __restrict__ pos_ids){
  int idx = blockIdx.x * 256 + threadIdx.x;   // 2^20 total: t(1) bh(5) s(11) d(3)
  int d = idx & 7;
  int s = (idx >> 3) & 2047;
  int bh = (idx >> 14) & 31;
  int tsel = idx >> 19;
  unsigned short* X = tsel ? Kb : Qb;
  size_t base = ((size_t)bh * S_ + s) * 64;
  float pos = (float)pos_ids[s];
  float freq = exp2f(-1.6609640474436813f * (float)d);  // 10000^(-d/8)
  float th = pos * freq;
  float sn = __sinf(th), cn = __cosf(th);
  float x0 = bf2f(X[base + d]), x1 = bf2f(X[base + d + 8]);
  X[base + d]     = f2bf(x0 * cn - x1 * sn);
  X[base + d + 8] = f2bf(x1 * cn + x0 * sn);
}

// ---------------- 4a: full-chip E + rinv precompute.
// WG per (bi, bh). E tile (bi,bj) at Eg[(bh*528 + tri(bi)+bj)*4096],
// quarter-major [w][16 rows][64 cols]. rinv_i = 1/(D+eps(D+E_ii)).
#define KST2 66
__launch_bounds__(256, 4)
__global__ void k_scores(const unsigned short* __restrict__ Qb,
                         const unsigned short* __restrict__ Kb,
                         unsigned short* __restrict__ Eg,
                         float* __restrict__ rinvg){
  __shared__ unsigned short Ks[64*KST2];
  __shared__ float dsh[4][16];
  const int bi = blockIdx.x >> 5, bh = blockIdx.x & 31;
  const unsigned short* Qh = Qb + (size_t)bh * S_ * 64;
  const unsigned short* Kh = Kb + (size_t)bh * S_ * 64;
  const int tid = threadIdx.x, w = tid >> 6, l = tid & 63;
  const int lq = l & 15, lh = l >> 4;
  const unsigned short* qp = Qh + (size_t)(bi*64 + w*16 + lq)*64 + lh*8;
  bf16x8 qf0 = *(const bf16x8*)(qp);
  bf16x8 qf1 = *(const bf16x8*)(qp + 32);
  float dacc[4] = {0.f,0.f,0.f,0.f};
  unsigned short* Etile0 = Eg + ((size_t)bh*528 + (size_t)(bi*(bi+1)/2))*4096;

  for (int bj = 0; bj <= bi; ++bj){
    __syncthreads();
    {
      int srow = tid >> 2, sc = (tid & 3)*16;
      const unsigned short* src = Kh + (size_t)(bj*64 + srow)*64 + sc;
      *(int4*)&Ks[srow*KST2 + sc]     = *(const int4*)(src);
      *(int4*)&Ks[srow*KST2 + sc + 8] = *(const int4*)(src + 8);
    }
    __syncthreads();
    unsigned short* Et = Etile0 + (size_t)bj*4096 + w*1024;
    const bool diag = (bj == bi);
    #pragma unroll
    for (int ct = 0; ct < 4; ++ct){
      bf16x8 b0 = *(const bf16x8*)&Ks[(ct*16 + lq)*KST2 + lh*8];
      bf16x8 b1 = *(const bf16x8*)&Ks[(ct*16 + lq)*KST2 + 32 + lh*8];
      f32x4 a = (f32x4){0.f,0.f,0.f,0.f};
      a = __builtin_amdgcn_mfma_f32_16x16x32_bf16(qf0, b0, a, 0, 0, 0);
      a = __builtin_amdgcn_mfma_f32_16x16x32_bf16(qf1, b1, a, 0, 0, 0);
      #pragma unroll
      for (int r = 0; r < 4; ++r){
        float e = __expf(a[r] * SCALEF);
        unsigned short eb = f2bf_trunc(e);
        int rrow = lh*4 + r, col = ct*16 + lq;
        Et[rrow*64 + col] = eb;
        float ev = bf2f(eb);
        int grow = w*16 + rrow;                 // global row within 64-block
        if (!diag || col < grow) dacc[r] += ev;
        if (diag && col == grow) dsh[w][rrow] = ev;
      }
    }
  }
  __syncthreads();
  #pragma unroll
  for (int r = 0; r < 4; ++r){
    float d = dacc[r];
    #pragma unroll
    for (int mm = 1; mm < 16; mm <<= 1) d += __shfl_xor(d, mm);
    float dE = dsh[w][lh*4 + r];
    float den = fmaf(EPSF, d + dE, d);
    float rv = 1.0f / den;
    if (lq == 0)
      rinvg[(size_t)bh*S_ + bi*64 + w*16 + lh*4 + r] = rv;
  }
}

// ---------------- 4b: striped recurrence with urgent/deferred pipeline.
// 4 WGs per head (128 WGs, 512 thr). blockIdx = s*32+bh (stripes share an XCD).
// Stripe s owns blocks {s, s+4, ...}. Per column bj:
//   top:    pre-issue ALL column-bj tile loads (c-independent) -> hidden.
//   phaseA: wave0 solves (if owner) or polls c; waves1-7 fold column bj-1's
//           DEFERRED units (c from csl[cur^1]).
//   phaseB: waves1-4 fold the URGENT tile (col bj -> block bj+1, owner only).
// COVERAGE (R11 bug): nd = (8-o0-ex)*4 reaches 32 when o0=0 AND ex=0
// (stripes 2,3 early columns) -> need 5 slots: t=(w-1)+k*7, k<5 covers t<=34;
// every t in [0,32) hit exactly once (w-1=t%7, k=t/7). 4 slots dropped units
// 28-31 = last owned block missing early columns (absmax 0.27).
__global__ __launch_bounds__(512)
__attribute__((amdgpu_waves_per_eu(2, 2)))   // VGPR budget 256: no spill
void k_recur3(const unsigned short* __restrict__ Eg,
              const float* __restrict__ rinvg,
              float* __restrict__ c_c,
              float* __restrict__ c_g){
  __shared__ float Pa[512];     // running P, owned block o at Pa[o*64+row]
  __shared__ float rso[512];    // rinv for owned rows
  __shared__ float csl[2][64];  // c double-buffer (by column parity)
  const int bh = blockIdx.x & 31, s = blockIdx.x >> 5;
  const unsigned short* Eh = Eg + (size_t)bh * 528 * 4096;
  const int tid = threadIdx.x, w = tid >> 6, l = tid & 63;
  const int lq = l & 15, lh = l >> 4;

  Pa[tid] = 0.f;
  rso[tid] = rinvg[(size_t)bh*S_ + (s + 4*w)*64 + l];
  __syncthreads();

  bf16x8 er[8];                 // wave 0: diag tile of next block to solve
  if (w == 0){
    const unsigned short* dt = Eh + ((size_t)(s*(s+1)/2) + s)*4096 + l*64;
    #pragma unroll
    for (int eb = 0; eb < 8; ++eb) er[eb] = *(const bf16x8*)(dt + eb*8);
  }

  bf16x8 dA0[5], dA1[5], dB0[5], dB1[5];   // deferred tile ping-pong sets
  bf16x8 ug0, ug1;                          // urgent tile regs
  const int lastc = s + 28;

  auto load_def = [&](int BJ, bf16x8 (&D0)[5], bf16x8 (&D1)[5]){
    int o0 = (BJ >= s) ? (((BJ - s) >> 2) + 1) : 0;
    int ex = (((BJ + 1) & 3) == s) ? 1 : 0;
    int nd = (8 - o0 - ex) * 4;
    if (w >= 1){
      #pragma unroll
      for (int k = 0; k < 5; ++k){
        int t = (w - 1) + k*7;
        if (t < nd){
          int ob = o0 + ex + (t >> 2);
          int bi = s + 4*ob;
          const unsigned short* tp =
              Eh + ((size_t)(bi*(bi+1)/2) + BJ)*4096 + (size_t)(t & 3)*1024;
          D0[k] = *(const bf16x8*)(tp + lq*64 + lh*8);
          D1[k] = *(const bf16x8*)(tp + lq*64 + 32 + lh*8);
        }
      }
      if (ex && w <= 4){
        int bi = BJ + 1;
        const unsigned short* tp =
            Eh + ((size_t)(bi*(bi+1)/2) + BJ)*4096 + (size_t)(w-1)*1024;
        ug0 = *(const bf16x8*)(tp + lq*64 + lh*8);
        ug1 = *(const bf16x8*)(tp + lq*64 + 32 + lh*8);
      }
    }
  };

  auto fold_def = [&](int BJP, bf16x8 (&D0)[5], bf16x8 (&D1)[5], int buf){
    int o0 = (BJP >= s) ? (((BJP - s) >> 2) + 1) : 0;
    int ex = (((BJP + 1) & 3) == s) ? 1 : 0;
    int nd = (8 - o0 - ex) * 4;
    if (w >= 1 && nd > 0){
      bf16x8 dc0 = (bf16x8){0,0,0,0,0,0,0,0};
      bf16x8 dc1 = (bf16x8){0,0,0,0,0,0,0,0};
      if (lq == 0){
        #pragma unroll
        for (int e = 0; e < 8; ++e){
          dc0[e] = (short)f2bf(csl[buf][lh*8 + e]);
          dc1[e] = (short)f2bf(csl[buf][32 + lh*8 + e]);
        }
      }
      #pragma unroll
      for (int k = 0; k < 5; ++k){
        int t = (w - 1) + k*7;
        if (t < nd){
          f32x4 o = (f32x4){0.f,0.f,0.f,0.f};
          o = __builtin_amdgcn_mfma_f32_16x16x32_bf16(D0[k], dc0, o, 0, 0, 0);
          o = __builtin_amdgcn_mfma_f32_16x16x32_bf16(D1[k], dc1, o, 0, 0, 0);
          if (lq == 0){
            int ob = o0 + ex + (t >> 2);
            float* base = Pa + ob*64 + (t & 3)*16 + lh*4;
            float4 v = *(float4*)base;
            v.x += o[0]; v.y += o[1]; v.z += o[2]; v.w += o[3];
            *(float4*)base = v;
          }
        }
      }
    }
  };

  auto iter = [&](int BJ, bf16x8 (&DL0)[5], bf16x8 (&DL1)[5],
                          bf16x8 (&DF0)[5], bf16x8 (&DF1)[5]){
    const int cur = BJ & 1;
    load_def(BJ, DL0, DL1);                 // pre-issue this column's tiles
    const int ex = (((BJ + 1) & 3) == s) ? 1 : 0;
    // ---- phase A: solve/poll(BJ) || deferred fold of column BJ-1
    if (w == 0){
      if ((BJ & 3) == s){
        const int rr = l;
        const int o = (BJ - s) >> 2;
        float rinv = rso[o*64 + rr];
        float Pl = Pa[o*64 + rr];
        float cval = 0.f;
        #pragma unroll
        for (int eb = 0; eb < 8; ++eb){
          #pragma unroll
          for (int e = 0; e < 8; ++e){
            int r = eb*8 + e;
            float t2 = Pl * rinv;
            float cr = __uint_as_float(
                (unsigned)__builtin_amdgcn_readlane(__float_as_uint(t2), r));
            if (BJ == 0 && r == 0) cr = 1.0f;
            if (rr == r) cval = cr;
            float m = (rr > r) ? bf2f((unsigned short)er[eb][e]) : 0.f;
            Pl = fmaf(m, cr, Pl);
          }
        }
        csl[cur][rr] = cval;
        __hip_atomic_store((unsigned*)(c_c + (size_t)bh*S_ + BJ*64 + rr),
                           __float_as_uint(cval),
                           __ATOMIC_RELAXED, __HIP_MEMORY_SCOPE_AGENT);
        c_g[((size_t)(bh >> 4)*S_ + (BJ*64 + rr))*16 + (bh & 15)] = cval;
        int bn = BJ + 4;                    // pre-issue next owned diag tile
        if (bn <= lastc){
          const unsigned short* dt =
              Eh + ((size_t)(bn*(bn+1)/2) + bn)*4096 + l*64;
          #pragma unroll
          for (int eb = 0; eb < 8; ++eb) er[eb] = *(const bf16x8*)(dt + eb*8);
        }
      } else {
        const unsigned* pp = (const unsigned*)(c_c + (size_t)bh*S_ + BJ*64 + l);
        unsigned v = __hip_atomic_load(pp, __ATOMIC_RELAXED,
                                       __HIP_MEMORY_SCOPE_AGENT);
        while (!__all(v != 0u)){
          __builtin_amdgcn_s_sleep(2);
          v = __hip_atomic_load(pp, __ATOMIC_RELAXED,
                                __HIP_MEMORY_SCOPE_AGENT);
        }
        csl[cur][l] = __uint_as_float(v);
      }
    } else if (BJ >= 1){
      fold_def(BJ - 1, DF0, DF1, cur ^ 1);
    }
    __syncthreads();
    // ---- phase B: urgent fold (col BJ -> block BJ+1), waves 1-4
    if (ex && w >= 1 && w <= 4){
      bf16x8 uc0 = (bf16x8){0,0,0,0,0,0,0,0};
      bf16x8 uc1 = (bf16x8){0,0,0,0,0,0,0,0};
      if (lq == 0){
        #pragma unroll
        for (int e = 0; e < 8; ++e){
          uc0[e] = (short)f2bf(csl[cur][lh*8 + e]);
          uc1[e] = (short)f2bf(csl[cur][32 + lh*8 + e]);
        }
      }
      f32x4 o = (f32x4){0.f,0.f,0.f,0.f};
      o = __builtin_amdgcn_mfma_f32_16x16x32_bf16(ug0, uc0, o, 0, 0, 0);
      o = __builtin_amdgcn_mfma_f32_16x16x32_bf16(ug1, uc1, o, 0, 0, 0);
      if (lq == 0){
        int ou = (BJ + 1 - s) >> 2;
        float* base = Pa + ou*64 + (w-1)*16 + lh*4;
        float4 v = *(float4*)base;
        v.x += o[0]; v.y += o[1]; v.z += o[2]; v.w += o[3];
        *(float4*)base = v;
      }
    }
    __syncthreads();
  };

  for (int bj = 0; bj <= lastc; bj += 2){
    iter(bj,     dA0, dA1, dB0, dB1);       // load A, fold B (col bj-1)
    if (bj + 1 <= lastc)
      iter(bj+1, dB0, dB1, dA0, dA1);       // load B, fold A (col bj)
  }
}

// ---------------- 5a: U[b,h,n] = sum_d v0[b,h,d] * Wd[h*64+d][n]
__global__ void k_u(const float* __restrict__ v0, const float* __restrict__ Wd,
                    float* __restrict__ U){
  int bh = blockIdx.x; int h = bh & 15;
  __shared__ float vsh[64];
  if (threadIdx.x < 64) vsh[threadIdx.x] = v0[bh*64 + threadIdx.x];
  __syncthreads();
  for (int n = threadIdx.x; n < 1024; n += 256){
    float acc = 0.f;
    #pragma unroll 8
    for (int d = 0; d < 64; ++d) acc = fmaf(vsh[d], Wd[(size_t)(h*64 + d)*1024 + n], acc);
    U[(size_t)bh*1024 + n] = acc;
  }
}

// ---------------- 5b: out[b,s,n] = bd[n] + sum_h c[b,s,h] * U[b,h,n]
__global__ void k_out(const float* __restrict__ c_g, const float* __restrict__ U,
                      const float* __restrict__ bd, float* __restrict__ out){
  int bs = blockIdx.x; int b = bs >> 11;
  __shared__ float ch[16];
  if (threadIdx.x < 16) ch[threadIdx.x] = c_g[(size_t)bs*16 + threadIdx.x];
  __syncthreads();
  int n = threadIdx.x * 4;
  float4 acc = *(const float4*)(bd + n);
  #pragma unroll
  for (int h = 0; h < 16; ++h){
    float cc = ch[h];
    float4 u = *(const float4*)(U + ((size_t)(b*16 + h))*1024 + n);
    acc.x = fmaf(cc, u.x, acc.x); acc.y = fmaf(cc, u.y, acc.y);
    acc.z = fmaf(cc, u.z, acc.z); acc.w = fmaf(cc, u.w, acc.w);
  }
  *(float4*)(out + (size_t)bs*1024 + n) = acc;
}

extern "C" void kernel_launch(void* const* d_in, const int* in_sizes, int n_in,
                              void* d_out, int out_size, void* d_ws, size_t ws_size,
                              hipStream_t stream) {
  const float* hs   = (const float*)d_in[0];   // [2][2048][1024]
  const int*   pos  = (const int*)d_in[1];     // [2048]
  const float* Wqkv = (const float*)d_in[2];   // [1024][3072]
  const float* bqkv = (const float*)d_in[3];   // [3072]
  const float* Wd   = (const float*)d_in[4];   // [1024][1024]
  const float* bd   = (const float*)d_in[5];   // [1024]
  float* out = (float*)d_out;

  // workspace layout
  char* ws = (char*)d_ws;
  unsigned short* Ab = (unsigned short*)(ws);                       // 8 MB
  unsigned short* WT = (unsigned short*)(ws + (8u<<20));            // 4 MB
  unsigned short* Qb = (unsigned short*)(ws + (12u<<20));           // 8 MB
  unsigned short* Kb = (unsigned short*)(ws + (20u<<20));           // 8 MB
  float* v0   = (float*)(ws + (28u<<20));                           // 8 KB
  float* c_g  = (float*)(ws + (28u<<20) + 0x10000);                 // 256 KB
  float* U    = (float*)(ws + (28u<<20) + 0x50000);                 // 128 KB
  float* rinvg= (float*)(ws + (28u<<20) + 0x80000);                 // 256 KB
  float* c_c  = (float*)(ws + (28u<<20) + 0xC0000);                 // 256 KB
  unsigned short* Eg = (unsigned short*)(ws + (29u<<20));           // 132 MB

  k_conv_a <<<4096, 256, 0, stream>>>(hs, Ab);
  k_conv_wt<<<dim3(64, 32), 256, 0, stream>>>(Wqkv, WT);
  k_v0     <<<32, 256, 0, stream>>>(hs, Wqkv, bqkv, v0);
  k_gemm_qk<<<dim3(16, 32), 256, 0, stream>>>(Ab, WT, bqkv, Qb, Kb);
  k_rope   <<<4096, 256, 0, stream>>>(Qb, Kb, pos);
  k_scores <<<1024, 256, 0, stream>>>(Qb, Kb, Eg, rinvg);
  hipMemsetAsync(c_c, 0, 32 * S_ * sizeof(float), stream);
  k_recur3 <<<128, 512, 0, stream>>>(Eg, rinvg, c_c, c_g);
  k_u      <<<32, 256, 0, stream>>>(v0, Wd, U);
  k_out    <<<4096, 256, 0, stream>>>(c_g, U, bd, out);
}

// Round 14
// 208.392 us; speedup vs baseline: 1.9385x; 1.0492x over previous
//
#include <hip/hip_runtime.h>

// Problem constants (B=2, S=2048, HIDDEN=1024, HEADS=16, HEAD_DIM=64, ROT=16)
#define S_ 2048
#define EPSF 1e-8f
#define SCALEF 0.125f

typedef short bf16x8 __attribute__((ext_vector_type(8)));
typedef float f32x4 __attribute__((ext_vector_type(4)));

__device__ __forceinline__ unsigned short f2bf(float f){
  unsigned int u = __float_as_uint(f);
  u = (u + 0x7fffu + ((u >> 16) & 1u)) >> 16;
  return (unsigned short)u;
}
__device__ __forceinline__ float bf2f(unsigned short h){
  return __uint_as_float(((unsigned int)h) << 16);
}
__device__ __forceinline__ unsigned short f2bf_trunc(float f){
  return (unsigned short)(__float_as_uint(f) >> 16);
}

// ---------------- 1: merged prep (conv_a | conv_wt | v0), role by blockIdx
__global__ void k_prep(const float* __restrict__ hs, const float* __restrict__ Wqkv,
                       const float* __restrict__ bqkv,
                       unsigned short* __restrict__ Ab,
                       unsigned short* __restrict__ WT,
                       float* __restrict__ v0){
  __shared__ float t[32][33];     // conv_wt path
  __shared__ float red[4][64];    // v0 path
  int bid = blockIdx.x;
  if (bid < 4096){
    // conv_a: fp32 -> bf16 of hidden_states [4096][1024]
    int i = (bid * 256 + threadIdx.x) * 4;
    float4 v = *(const float4*)(hs + i);
    ushort4 o; o.x=f2bf(v.x); o.y=f2bf(v.y); o.z=f2bf(v.z); o.w=f2bf(v.w);
    *(ushort4*)(Ab + i) = o;
  } else if (bid < 6144){
    // conv_wt: Wqkv cols [0,2048) -> WT bf16 [2048][1024] transposed
    int q = bid - 4096;
    int nt = q & 63, kt = q >> 6;
    int tx = threadIdx.x & 31, ty = threadIdx.x >> 5;   // 32 x 8
    #pragma unroll
    for (int r = 0; r < 32; r += 8)
      t[ty + r][tx] = Wqkv[(size_t)(kt*32 + ty + r)*3072 + nt*32 + tx];
    __syncthreads();
    #pragma unroll
    for (int r = 0; r < 32; r += 8)
      WT[(size_t)(nt*32 + ty + r)*1024 + kt*32 + tx] = f2bf(t[tx][ty + r]);
  } else {
    // v0[b,h,d] = hs[b,0,:] @ Wqkv[:, 2048+h*64+d] + bqkv
    int bh = bid - 6144; int b = bh >> 4;
    int d = threadIdx.x & 63, kc = threadIdx.x >> 6;
    const float* x = hs + (size_t)b * S_ * 1024;
    int col = 2048 + (bh & 15)*64 + d;
    float acc = 0.f;
    #pragma unroll 8
    for (int k = kc*256; k < kc*256 + 256; ++k)
      acc = fmaf(x[k], Wqkv[(size_t)k*3072 + col], acc);
    red[kc][d] = acc;
    __syncthreads();
    if (kc == 0)
      v0[bh*64 + d] = red[0][d] + red[1][d] + red[2][d] + red[3][d] + bqkv[col];
  }
}

// ---------------- 2: QK projection GEMM + fused RoPE epilogue.
// M=4096 N=2048 K=1024 bf16 MFMA. Rotary dims d<16 live in j==0 tiles
// (d = j*16 + lq); pair (d, d+8) = lanes (l, l^8) -> one __shfl_xor.
// Rotation in fp32 pre-round (MORE accurate than old bf16 round-trip).
#define GSTRIDE 72   // LDS row stride in bf16 elems
__launch_bounds__(256)
__global__ void k_gemm_qk(const unsigned short* __restrict__ Ab,
                          const unsigned short* __restrict__ WT,
                          const float* __restrict__ bqkv,
                          const int* __restrict__ pos_ids,
                          unsigned short* __restrict__ Qb,
                          unsigned short* __restrict__ Kb){
  __shared__ unsigned short At[128*GSTRIDE];
  __shared__ unsigned short Bt[128*GSTRIDE];
  const int m0 = blockIdx.y * 128, n0 = blockIdx.x * 128;
  const int w = threadIdx.x >> 6, l = threadIdx.x & 63;
  const int wr = w >> 1, wc = w & 1;
  f32x4 acc[4][4];
  #pragma unroll
  for (int i = 0; i < 4; ++i)
    #pragma unroll
    for (int j = 0; j < 4; ++j) acc[i][j] = (f32x4){0.f,0.f,0.f,0.f};

  const int srow = threadIdx.x >> 1;
  const int sseg = (threadIdx.x & 1) * 2;

  for (int kt = 0; kt < 1024; kt += 32){
    int4 va0 = *(const int4*)(Ab + (size_t)(m0+srow)*1024 + kt + sseg*8);
    int4 va1 = *(const int4*)(Ab + (size_t)(m0+srow)*1024 + kt + sseg*8 + 8);
    int4 vb0 = *(const int4*)(WT + (size_t)(n0+srow)*1024 + kt + sseg*8);
    int4 vb1 = *(const int4*)(WT + (size_t)(n0+srow)*1024 + kt + sseg*8 + 8);
    *(int4*)&At[srow*GSTRIDE + sseg*8]     = va0;
    *(int4*)&At[srow*GSTRIDE + sseg*8 + 8] = va1;
    *(int4*)&Bt[srow*GSTRIDE + sseg*8]     = vb0;
    *(int4*)&Bt[srow*GSTRIDE + sseg*8 + 8] = vb1;
    __syncthreads();
    bf16x8 af[4], bf[4];
    #pragma unroll
    for (int i = 0; i < 4; ++i)
      af[i] = *(const bf16x8*)&At[(wr*64 + i*16 + (l&15))*GSTRIDE + (l>>4)*8];
    #pragma unroll
    for (int j = 0; j < 4; ++j)
      bf[j] = *(const bf16x8*)&Bt[(wc*64 + j*16 + (l&15))*GSTRIDE + (l>>4)*8];
    #pragma unroll
    for (int i = 0; i < 4; ++i)
      #pragma unroll
      for (int j = 0; j < 4; ++j)
        acc[i][j] = __builtin_amdgcn_mfma_f32_16x16x32_bf16(af[i], bf[j], acc[i][j], 0, 0, 0);
    __syncthreads();
  }
  #pragma unroll
  for (int i = 0; i < 4; ++i){
    #pragma unroll
    for (int j = 0; j < 4; ++j){
      #pragma unroll
      for (int r = 0; r < 4; ++r){
        int m = m0 + wr*64 + i*16 + (l>>4)*4 + r;
        int n = n0 + wc*64 + j*16 + (l&15);
        float v = acc[i][j][r] + bqkv[n];
        if (j == 0){   // rotary dims d = lq < 16
          float partner = __shfl_xor(v, 8);
          int s = m & 2047;
          float pos = (float)pos_ids[s];
          float fr = exp2f(-1.6609640474436813f * (float)(l & 7));
          float th = pos * fr;
          float sn = __sinf(th), cn = __cosf(th);
          v = ((l & 8) == 0) ? (v*cn - partner*sn) : (v*cn + partner*sn);
        }
        int b = m >> 11, s2 = m & 2047;
        int tsel = n >> 10; int nq = n & 1023;
        int h = nq >> 6, d = nq & 63;
        unsigned short* dst = tsel ? Kb : Qb;
        dst[((size_t)(b*16 + h)*S_ + s2)*64 + d] = f2bf(v);
      }
    }
  }
}

// ---------------- 4a: full-chip E + rinv precompute (v2).
// WG per (bi, bh). E tile (bi,bj) at Eg[(bh*528 + tri(bi)+bj)*4096],
// quarter-major [w][16 rows][64 cols]. rinv_i = 1/(D+eps(D+E_ii)).
// v2: K double-buffer (1 barrier/stage, load hidden under compute) and
// coalesced E-stores (per-wave LDS tile -> 2x int4 1KB stores per quarter,
// vs 64x 2B scattered).
#define KST2 66
#define EST 68
__launch_bounds__(256, 4)
__global__ void k_scores(const unsigned short* __restrict__ Qb,
                         const unsigned short* __restrict__ Kb,
                         unsigned short* __restrict__ Eg,
                         float* __restrict__ rinvg){
  __shared__ unsigned short Ks[2][64*KST2];
  __shared__ unsigned short Es[4][16*EST];
  __shared__ float dsh[4][16];
  const int bi = blockIdx.x >> 5, bh = blockIdx.x & 31;
  const unsigned short* Qh = Qb + (size_t)bh * S_ * 64;
  const unsigned short* Kh = Kb + (size_t)bh * S_ * 64;
  const int tid = threadIdx.x, w = tid >> 6, l = tid & 63;
  const int lq = l & 15, lh = l >> 4;
  const unsigned short* qp = Qh + (size_t)(bi*64 + w*16 + lq)*64 + lh*8;
  bf16x8 qf0 = *(const bf16x8*)(qp);
  bf16x8 qf1 = *(const bf16x8*)(qp + 32);
  float dacc[4] = {0.f,0.f,0.f,0.f};
  unsigned short* Etile0 = Eg + ((size_t)bh*528 + (size_t)(bi*(bi+1)/2))*4096;
  const int srow = tid >> 2, sc = (tid & 3)*16;

  { // prologue: stage K block 0 into buf 0
    const unsigned short* src = Kh + (size_t)srow*64 + sc;
    *(int4*)&Ks[0][srow*KST2 + sc]     = *(const int4*)(src);
    *(int4*)&Ks[0][srow*KST2 + sc + 8] = *(const int4*)(src + 8);
  }
  __syncthreads();

  for (int bj = 0; bj <= bi; ++bj){
    const int cur = bj & 1;
    int4 nk0, nk1;
    if (bj < bi){  // issue next K-block loads (hidden under compute)
      const unsigned short* src = Kh + (size_t)((bj+1)*64 + srow)*64 + sc;
      nk0 = *(const int4*)(src);
      nk1 = *(const int4*)(src + 8);
    }
    unsigned short* Et = Etile0 + (size_t)bj*4096 + w*1024;
    const bool diag = (bj == bi);
    #pragma unroll
    for (int ct = 0; ct < 4; ++ct){
      bf16x8 b0 = *(const bf16x8*)&Ks[cur][(ct*16 + lq)*KST2 + lh*8];
      bf16x8 b1 = *(const bf16x8*)&Ks[cur][(ct*16 + lq)*KST2 + 32 + lh*8];
      f32x4 a = (f32x4){0.f,0.f,0.f,0.f};
      a = __builtin_amdgcn_mfma_f32_16x16x32_bf16(qf0, b0, a, 0, 0, 0);
      a = __builtin_amdgcn_mfma_f32_16x16x32_bf16(qf1, b1, a, 0, 0, 0);
      #pragma unroll
      for (int r = 0; r < 4; ++r){
        float e = __expf(a[r] * SCALEF);
        unsigned short eb = f2bf_trunc(e);
        int rrow = lh*4 + r, col = ct*16 + lq;
        Es[w][rrow*EST + col] = eb;
        float ev = bf2f(eb);
        int grow = w*16 + rrow;                 // global row within 64-block
        if (!diag || col < grow) dacc[r] += ev;
        if (diag && col == grow) dsh[w][rrow] = ev;
      }
    }
    // coalesced write-out: 2 instrs x 1KB contiguous per quarter
    #pragma unroll
    for (int it = 0; it < 2; ++it){
      int row = it*8 + (l >> 3), eo = (l & 7)*8;
      *(int4*)(Et + row*64 + eo) = *(const int4*)&Es[w][row*EST + eo];
    }
    if (bj < bi){  // write next K-block to the other buffer
      *(int4*)&Ks[cur^1][srow*KST2 + sc]     = nk0;
      *(int4*)&Ks[cur^1][srow*KST2 + sc + 8] = nk1;
    }
    __syncthreads();
  }
  #pragma unroll
  for (int r = 0; r < 4; ++r){
    float d = dacc[r];
    #pragma unroll
    for (int mm = 1; mm < 16; mm <<= 1) d += __shfl_xor(d, mm);
    float dE = dsh[w][lh*4 + r];
    float den = fmaf(EPSF, d + dE, d);
    float rv = 1.0f / den;
    if (lq == 0)
      rinvg[(size_t)bh*S_ + bi*64 + w*16 + lh*4 + r] = rv;
  }
}

// ---------------- 4b: striped recurrence with urgent/deferred pipeline.
// (unchanged from R12 — known-good at 87 µs)
__global__ __launch_bounds__(512)
__attribute__((amdgpu_waves_per_eu(2, 2)))   // VGPR budget 256: no spill
void k_recur3(const unsigned short* __restrict__ Eg,
              const float* __restrict__ rinvg,
              float* __restrict__ c_c,
              float* __restrict__ c_g){
  __shared__ float Pa[512];     // running P, owned block o at Pa[o*64+row]
  __shared__ float rso[512];    // rinv for owned rows
  __shared__ float csl[2][64];  // c double-buffer (by column parity)
  const int bh = blockIdx.x & 31, s = blockIdx.x >> 5;
  const unsigned short* Eh = Eg + (size_t)bh * 528 * 4096;
  const int tid = threadIdx.x, w = tid >> 6, l = tid & 63;
  const int lq = l & 15, lh = l >> 4;

  Pa[tid] = 0.f;
  rso[tid] = rinvg[(size_t)bh*S_ + (s + 4*w)*64 + l];
  __syncthreads();

  bf16x8 er[8];                 // wave 0: diag tile of next block to solve
  if (w == 0){
    const unsigned short* dt = Eh + ((size_t)(s*(s+1)/2) + s)*4096 + l*64;
    #pragma unroll
    for (int eb = 0; eb < 8; ++eb) er[eb] = *(const bf16x8*)(dt + eb*8);
  }

  bf16x8 dA0[5], dA1[5], dB0[5], dB1[5];   // deferred tile ping-pong sets
  bf16x8 ug0, ug1;                          // urgent tile regs
  const int lastc = s + 28;

  auto load_def = [&](int BJ, bf16x8 (&D0)[5], bf16x8 (&D1)[5]){
    int o0 = (BJ >= s) ? (((BJ - s) >> 2) + 1) : 0;
    int ex = (((BJ + 1) & 3) == s) ? 1 : 0;
    int nd = (8 - o0 - ex) * 4;
    if (w >= 1){
      #pragma unroll
      for (int k = 0; k < 5; ++k){
        int t = (w - 1) + k*7;
        if (t < nd){
          int ob = o0 + ex + (t >> 2);
          int bi = s + 4*ob;
          const unsigned short* tp =
              Eh + ((size_t)(bi*(bi+1)/2) + BJ)*4096 + (size_t)(t & 3)*1024;
          D0[k] = *(const bf16x8*)(tp + lq*64 + lh*8);
          D1[k] = *(const bf16x8*)(tp + lq*64 + 32 + lh*8);
        }
      }
      if (ex && w <= 4){
        int bi = BJ + 1;
        const unsigned short* tp =
            Eh + ((size_t)(bi*(bi+1)/2) + BJ)*4096 + (size_t)(w-1)*1024;
        ug0 = *(const bf16x8*)(tp + lq*64 + lh*8);
        ug1 = *(const bf16x8*)(tp + lq*64 + 32 + lh*8);
      }
    }
  };

  auto fold_def = [&](int BJP, bf16x8 (&D0)[5], bf16x8 (&D1)[5], int buf){
    int o0 = (BJP >= s) ? (((BJP - s) >> 2) + 1) : 0;
    int ex = (((BJP + 1) & 3) == s) ? 1 : 0;
    int nd = (8 - o0 - ex) * 4;
    if (w >= 1 && nd > 0){
      bf16x8 dc0 = (bf16x8){0,0,0,0,0,0,0,0};
      bf16x8 dc1 = (bf16x8){0,0,0,0,0,0,0,0};
      if (lq == 0){
        #pragma unroll
        for (int e = 0; e < 8; ++e){
          dc0[e] = (short)f2bf(csl[buf][lh*8 + e]);
          dc1[e] = (short)f2bf(csl[buf][32 + lh*8 + e]);
        }
      }
      #pragma unroll
      for (int k = 0; k < 5; ++k){
        int t = (w - 1) + k*7;
        if (t < nd){
          f32x4 o = (f32x4){0.f,0.f,0.f,0.f};
          o = __builtin_amdgcn_mfma_f32_16x16x32_bf16(D0[k], dc0, o, 0, 0, 0);
          o = __builtin_amdgcn_mfma_f32_16x16x32_bf16(D1[k], dc1, o, 0, 0, 0);
          if (lq == 0){
            int ob = o0 + ex + (t >> 2);
            float* base = Pa + ob*64 + (t & 3)*16 + lh*4;
            float4 v = *(float4*)base;
            v.x += o[0]; v.y += o[1]; v.z += o[2]; v.w += o[3];
            *(float4*)base = v;
          }
        }
      }
    }
  };

  auto iter = [&](int BJ, bf16x8 (&DL0)[5], bf16x8 (&DL1)[5],
                          bf16x8 (&DF0)[5], bf16x8 (&DF1)[5]){
    const int cur = BJ & 1;
    load_def(BJ, DL0, DL1);                 // pre-issue this column's tiles
    const int ex = (((BJ + 1) & 3) == s) ? 1 : 0;
    // ---- phase A: solve/poll(BJ) || deferred fold of column BJ-1
    if (w == 0){
      if ((BJ & 3) == s){
        const int rr = l;
        const int o = (BJ - s) >> 2;
        float rinv = rso[o*64 + rr];
        float Pl = Pa[o*64 + rr];
        float cval = 0.f;
        #pragma unroll
        for (int eb = 0; eb < 8; ++eb){
          #pragma unroll
          for (int e = 0; e < 8; ++e){
            int r = eb*8 + e;
            float t2 = Pl * rinv;
            float cr = __uint_as_float(
                (unsigned)__builtin_amdgcn_readlane(__float_as_uint(t2), r));
            if (BJ == 0 && r == 0) cr = 1.0f;
            if (rr == r) cval = cr;
            float m = (rr > r) ? bf2f((unsigned short)er[eb][e]) : 0.f;
            Pl = fmaf(m, cr, Pl);
          }
        }
        csl[cur][rr] = cval;
        __hip_atomic_store((unsigned*)(c_c + (size_t)bh*S_ + BJ*64 + rr),
                           __float_as_uint(cval),
                           __ATOMIC_RELAXED, __HIP_MEMORY_SCOPE_AGENT);
        c_g[((size_t)(bh >> 4)*S_ + (BJ*64 + rr))*16 + (bh & 15)] = cval;
        int bn = BJ + 4;                    // pre-issue next owned diag tile
        if (bn <= lastc){
          const unsigned short* dt =
              Eh + ((size_t)(bn*(bn+1)/2) + bn)*4096 + l*64;
          #pragma unroll
          for (int eb = 0; eb < 8; ++eb) er[eb] = *(const bf16x8*)(dt + eb*8);
        }
      } else {
        const unsigned* pp = (const unsigned*)(c_c + (size_t)bh*S_ + BJ*64 + l);
        unsigned v = __hip_atomic_load(pp, __ATOMIC_RELAXED,
                                       __HIP_MEMORY_SCOPE_AGENT);
        while (!__all(v != 0u)){
          __builtin_amdgcn_s_sleep(2);
          v = __hip_atomic_load(pp, __ATOMIC_RELAXED,
                                __HIP_MEMORY_SCOPE_AGENT);
        }
        csl[cur][l] = __uint_as_float(v);
      }
    } else if (BJ >= 1){
      fold_def(BJ - 1, DF0, DF1, cur ^ 1);
    }
    __syncthreads();
    // ---- phase B: urgent fold (col BJ -> block BJ+1), waves 1-4
    if (ex && w >= 1 && w <= 4){
      bf16x8 uc0 = (bf16x8){0,0,0,0,0,0,0,0};
      bf16x8 uc1 = (bf16x8){0,0,0,0,0,0,0,0};
      if (lq == 0){
        #pragma unroll
        for (int e = 0; e < 8; ++e){
          uc0[e] = (short)f2bf(csl[cur][lh*8 + e]);
          uc1[e] = (short)f2bf(csl[cur][32 + lh*8 + e]);
        }
      }
      f32x4 o = (f32x4){0.f,0.f,0.f,0.f};
      o = __builtin_amdgcn_mfma_f32_16x16x32_bf16(ug0, uc0, o, 0, 0, 0);
      o = __builtin_amdgcn_mfma_f32_16x16x32_bf16(ug1, uc1, o, 0, 0, 0);
      if (lq == 0){
        int ou = (BJ + 1 - s) >> 2;
        float* base = Pa + ou*64 + (w-1)*16 + lh*4;
        float4 v = *(float4*)base;
        v.x += o[0]; v.y += o[1]; v.z += o[2]; v.w += o[3];
        *(float4*)base = v;
      }
    }
    __syncthreads();
  };

  for (int bj = 0; bj <= lastc; bj += 2){
    iter(bj,     dA0, dA1, dB0, dB1);       // load A, fold B (col bj-1)
    if (bj + 1 <= lastc)
      iter(bj+1, dB0, dB1, dA0, dA1);       // load B, fold A (col bj)
  }
}

// ---------------- 5a: U[b,h,n] = sum_d v0[b,h,d] * Wd[h*64+d][n]
__global__ void k_u(const float* __restrict__ v0, const float* __restrict__ Wd,
                    float* __restrict__ U){
  int bh = blockIdx.x; int h = bh & 15;
  __shared__ float vsh[64];
  if (threadIdx.x < 64) vsh[threadIdx.x] = v0[bh*64 + threadIdx.x];
  __syncthreads();
  for (int n = threadIdx.x; n < 1024; n += 256){
    float acc = 0.f;
    #pragma unroll 8
    for (int d = 0; d < 64; ++d) acc = fmaf(vsh[d], Wd[(size_t)(h*64 + d)*1024 + n], acc);
    U[(size_t)bh*1024 + n] = acc;
  }
}

// ---------------- 5b: out[b,s,n] = bd[n] + sum_h c[b,s,h] * U[b,h,n]
__global__ void k_out(const float* __restrict__ c_g, const float* __restrict__ U,
                      const float* __restrict__ bd, float* __restrict__ out){
  int bs = blockIdx.x; int b = bs >> 11;
  __shared__ float ch[16];
  if (threadIdx.x < 16) ch[threadIdx.x] = c_g[(size_t)bs*16 + threadIdx.x];
  __syncthreads();
  int n = threadIdx.x * 4;
  float4 acc = *(const float4*)(bd + n);
  #pragma unroll
  for (int h = 0; h < 16; ++h){
    float cc = ch[h];
    float4 u = *(const float4*)(U + ((size_t)(b*16 + h))*1024 + n);
    acc.x = fmaf(cc, u.x, acc.x); acc.y = fmaf(cc, u.y, acc.y);
    acc.z = fmaf(cc, u.z, acc.z); acc.w = fmaf(cc, u.w, acc.w);
  }
  *(float4*)(out + (size_t)bs*1024 + n) = acc;
}

extern "C" void kernel_launch(void* const* d_in, const int* in_sizes, int n_in,
                              void* d_out, int out_size, void* d_ws, size_t ws_size,
                              hipStream_t stream) {
  const float* hs   = (const float*)d_in[0];   // [2][2048][1024]
  const int*   pos  = (const int*)d_in[1];     // [2048]
  const float* Wqkv = (const float*)d_in[2];   // [1024][3072]
  const float* bqkv = (const float*)d_in[3];   // [3072]
  const float* Wd   = (const float*)d_in[4];   // [1024][1024]
  const float* bd   = (const float*)d_in[5];   // [1024]
  float* out = (float*)d_out;

  // workspace layout
  char* ws = (char*)d_ws;
  unsigned short* Ab = (unsigned short*)(ws);                       // 8 MB
  unsigned short* WT = (unsigned short*)(ws + (8u<<20));            // 4 MB
  unsigned short* Qb = (unsigned short*)(ws + (12u<<20));           // 8 MB
  unsigned short* Kb = (unsigned short*)(ws + (20u<<20));           // 8 MB
  float* v0   = (float*)(ws + (28u<<20));                           // 8 KB
  float* c_g  = (float*)(ws + (28u<<20) + 0x10000);                 // 256 KB
  float* U    = (float*)(ws + (28u<<20) + 0x50000);                 // 128 KB
  float* rinvg= (float*)(ws + (28u<<20) + 0x80000);                 // 256 KB
  float* c_c  = (float*)(ws + (28u<<20) + 0xC0000);                 // 256 KB
  unsigned short* Eg = (unsigned short*)(ws + (29u<<20));           // 132 MB

  k_prep   <<<6176, 256, 0, stream>>>(hs, Wqkv, bqkv, Ab, WT, v0);
  k_gemm_qk<<<dim3(16, 32), 256, 0, stream>>>(Ab, WT, bqkv, pos, Qb, Kb);
  k_scores <<<1024, 256, 0, stream>>>(Qb, Kb, Eg, rinvg);
  hipMemsetAsync(c_c, 0, 32 * S_ * sizeof(float), stream);
  k_recur3 <<<128, 512, 0, stream>>>(Eg, rinvg, c_c, c_g);
  k_u      <<<32, 256, 0, stream>>>(v0, Wd, U);
  k_out    <<<4096, 256, 0, stream>>>(c_g, U, bd, out);
}

// Round 15
// 201.836 us; speedup vs baseline: 2.0015x; 1.0325x over previous
//
#include <hip/hip_runtime.h>

// Problem constants (B=2, S=2048, HIDDEN=1024, HEADS=16, HEAD_DIM=64, ROT=16)
#define S_ 2048
#define EPSF 1e-8f
#define SCALEF 0.125f

typedef short bf16x8 __attribute__((ext_vector_type(8)));
typedef float f32x4 __attribute__((ext_vector_type(4)));

__device__ __forceinline__ unsigned short f2bf(float f){
  unsigned int u = __float_as_uint(f);
  u = (u + 0x7fffu + ((u >> 16) & 1u)) >> 16;
  return (unsigned short)u;
}
__device__ __forceinline__ float bf2f(unsigned short h){
  return __uint_as_float(((unsigned int)h) << 16);
}
__device__ __forceinline__ unsigned short f2bf_trunc(float f){
  return (unsigned short)(__float_as_uint(f) >> 16);
}

#define GLD16(g, l) __builtin_amdgcn_global_load_lds( \
    (const __attribute__((address_space(1))) unsigned int*)(g), \
    (__attribute__((address_space(3))) unsigned int*)(l), 16, 0, 0)

// ---------------- 1: merged prep (conv_a | conv_wt | v0+U), role by blockIdx
__global__ void k_prep(const float* __restrict__ hs, const float* __restrict__ Wqkv,
                       const float* __restrict__ bqkv, const float* __restrict__ Wd,
                       unsigned short* __restrict__ Ab,
                       unsigned short* __restrict__ WT,
                       float* __restrict__ U){
  __shared__ float t[32][33];     // conv_wt path
  __shared__ float red[4][64];    // v0 path
  __shared__ float vsh[64];
  int bid = blockIdx.x;
  if (bid < 4096){
    // conv_a: fp32 -> bf16 of hidden_states [4096][1024]
    int i = (bid * 256 + threadIdx.x) * 4;
    float4 v = *(const float4*)(hs + i);
    ushort4 o; o.x=f2bf(v.x); o.y=f2bf(v.y); o.z=f2bf(v.z); o.w=f2bf(v.w);
    *(ushort4*)(Ab + i) = o;
  } else if (bid < 6144){
    // conv_wt: Wqkv cols [0,2048) -> WT bf16 [2048][1024] transposed
    int q = bid - 4096;
    int nt = q & 63, kt = q >> 6;
    int tx = threadIdx.x & 31, ty = threadIdx.x >> 5;   // 32 x 8
    #pragma unroll
    for (int r = 0; r < 32; r += 8)
      t[ty + r][tx] = Wqkv[(size_t)(kt*32 + ty + r)*3072 + nt*32 + tx];
    __syncthreads();
    #pragma unroll
    for (int r = 0; r < 32; r += 8)
      WT[(size_t)(nt*32 + ty + r)*1024 + kt*32 + tx] = f2bf(t[tx][ty + r]);
  } else {
    // v0[b,h,:] = hs[b,0,:] @ Wqkv[:, 2048+h*64+:] + bqkv  (exact fp32)
    // then U[bh,n] = sum_d v0[d] * Wd[h*64+d][n]  (k_u fused here)
    int bh = bid - 6144; int b = bh >> 4, h = bh & 15;
    int d = threadIdx.x & 63, kc = threadIdx.x >> 6;
    const float* x = hs + (size_t)b * S_ * 1024;
    int col = 2048 + h*64 + d;
    float acc = 0.f;
    #pragma unroll 8
    for (int k = kc*256; k < kc*256 + 256; ++k)
      acc = fmaf(x[k], Wqkv[(size_t)k*3072 + col], acc);
    red[kc][d] = acc;
    __syncthreads();
    if (kc == 0)
      vsh[d] = red[0][d] + red[1][d] + red[2][d] + red[3][d] + bqkv[col];
    __syncthreads();
    for (int n = threadIdx.x; n < 1024; n += 256){
      float a2 = 0.f;
      #pragma unroll 8
      for (int dd = 0; dd < 64; ++dd)
        a2 = fmaf(vsh[dd], Wd[(size_t)(h*64 + dd)*1024 + n], a2);
      U[(size_t)bh*1024 + n] = a2;
    }
  }
}

// ---------------- 2: QK projection GEMM + fused RoPE epilogue.
// M=4096 N=2048 K=1024 bf16 MFMA, m97 structure: global_load_lds width-16
// into LINEAR LDS [128][32] (no padding — gload_lds writes base+lane*16).
// Per wave per K-step: 2 A-instrs + 2 B-instrs, each 1KB = 16 rows x 64B
// (lane i -> row i/4, 16B chunk i%4). RoPE fused in epilogue (d<16 <=> j==0;
// pair (d,d+8) = lanes (l, l^8) via __shfl_xor, rotated in fp32 pre-round).
#define BK 32
__launch_bounds__(256)
__global__ void k_gemm_qk(const unsigned short* __restrict__ Ab,
                          const unsigned short* __restrict__ WT,
                          const float* __restrict__ bqkv,
                          const int* __restrict__ pos_ids,
                          unsigned short* __restrict__ Qb,
                          unsigned short* __restrict__ Kb){
  __shared__ unsigned short At[128*BK];   // 8 KB, linear
  __shared__ unsigned short Bt[128*BK];   // 8 KB, linear
  const int m0 = blockIdx.y * 128, n0 = blockIdx.x * 128;
  const int w = threadIdx.x >> 6, l = threadIdx.x & 63;
  const int wr = w >> 1, wc = w & 1;
  const int lq = l & 15, lh = l >> 4;
  f32x4 acc[4][4];
  #pragma unroll
  for (int i = 0; i < 4; ++i)
    #pragma unroll
    for (int j = 0; j < 4; ++j) acc[i][j] = (f32x4){0.f,0.f,0.f,0.f};

  const int srow = l >> 2;          // 0..15 (row within 16-row group)
  const int scol = (l & 3) * 8;     // bf16 offset (16B chunk)

  for (int kt = 0; kt < 1024; kt += BK){
    // stage A rows [w*32, w*32+32) and B rows [w*32, w*32+32), direct to LDS
    GLD16(Ab + (size_t)(m0 + w*32 +      srow)*1024 + kt + scol, &At[(w*32)*BK]);
    GLD16(Ab + (size_t)(m0 + w*32 + 16 + srow)*1024 + kt + scol, &At[(w*32+16)*BK]);
    GLD16(WT + (size_t)(n0 + w*32 +      srow)*1024 + kt + scol, &Bt[(w*32)*BK]);
    GLD16(WT + (size_t)(n0 + w*32 + 16 + srow)*1024 + kt + scol, &Bt[(w*32+16)*BK]);
    __syncthreads();
    bf16x8 af[4], bf[4];
    #pragma unroll
    for (int i = 0; i < 4; ++i)
      af[i] = *(const bf16x8*)&At[(wr*64 + i*16 + lq)*BK + lh*8];
    #pragma unroll
    for (int j = 0; j < 4; ++j)
      bf[j] = *(const bf16x8*)&Bt[(wc*64 + j*16 + lq)*BK + lh*8];
    #pragma unroll
    for (int i = 0; i < 4; ++i)
      #pragma unroll
      for (int j = 0; j < 4; ++j)
        acc[i][j] = __builtin_amdgcn_mfma_f32_16x16x32_bf16(af[i], bf[j], acc[i][j], 0, 0, 0);
    __syncthreads();
  }
  #pragma unroll
  for (int i = 0; i < 4; ++i){
    #pragma unroll
    for (int j = 0; j < 4; ++j){
      #pragma unroll
      for (int r = 0; r < 4; ++r){
        int m = m0 + wr*64 + i*16 + (l>>4)*4 + r;
        int n = n0 + wc*64 + j*16 + (l&15);
        float v = acc[i][j][r] + bqkv[n];
        if (j == 0){   // rotary dims d = lq < 16
          float partner = __shfl_xor(v, 8);
          int s = m & 2047;
          float pos = (float)pos_ids[s];
          float fr = exp2f(-1.6609640474436813f * (float)(l & 7));
          float th = pos * fr;
          float sn = __sinf(th), cn = __cosf(th);
          v = ((l & 8) == 0) ? (v*cn - partner*sn) : (v*cn + partner*sn);
        }
        int b = m >> 11, s2 = m & 2047;
        int tsel = n >> 10; int nq = n & 1023;
        int h = nq >> 6, d = nq & 63;
        unsigned short* dst = tsel ? Kb : Qb;
        dst[((size_t)(b*16 + h)*S_ + s2)*64 + d] = f2bf(v);
      }
    }
  }
}

// ---------------- 4a: full-chip E + rinv precompute (v2).
// WG per (bi, bh). E tile (bi,bj) at Eg[(bh*528 + tri(bi)+bj)*4096],
// quarter-major [w][16 rows][64 cols]. rinv_i = 1/(D+eps(D+E_ii)).
#define KST2 66
#define EST 68
__launch_bounds__(256, 4)
__global__ void k_scores(const unsigned short* __restrict__ Qb,
                         const unsigned short* __restrict__ Kb,
                         unsigned short* __restrict__ Eg,
                         float* __restrict__ rinvg){
  __shared__ unsigned short Ks[2][64*KST2];
  __shared__ unsigned short Es[4][16*EST];
  __shared__ float dsh[4][16];
  const int bi = blockIdx.x >> 5, bh = blockIdx.x & 31;
  const unsigned short* Qh = Qb + (size_t)bh * S_ * 64;
  const unsigned short* Kh = Kb + (size_t)bh * S_ * 64;
  const int tid = threadIdx.x, w = tid >> 6, l = tid & 63;
  const int lq = l & 15, lh = l >> 4;
  const unsigned short* qp = Qh + (size_t)(bi*64 + w*16 + lq)*64 + lh*8;
  bf16x8 qf0 = *(const bf16x8*)(qp);
  bf16x8 qf1 = *(const bf16x8*)(qp + 32);
  float dacc[4] = {0.f,0.f,0.f,0.f};
  unsigned short* Etile0 = Eg + ((size_t)bh*528 + (size_t)(bi*(bi+1)/2))*4096;
  const int srow = tid >> 2, sc = (tid & 3)*16;

  { // prologue: stage K block 0 into buf 0
    const unsigned short* src = Kh + (size_t)srow*64 + sc;
    *(int4*)&Ks[0][srow*KST2 + sc]     = *(const int4*)(src);
    *(int4*)&Ks[0][srow*KST2 + sc + 8] = *(const int4*)(src + 8);
  }
  __syncthreads();

  for (int bj = 0; bj <= bi; ++bj){
    const int cur = bj & 1;
    int4 nk0, nk1;
    if (bj < bi){
      const unsigned short* src = Kh + (size_t)((bj+1)*64 + srow)*64 + sc;
      nk0 = *(const int4*)(src);
      nk1 = *(const int4*)(src + 8);
    }
    unsigned short* Et = Etile0 + (size_t)bj*4096 + w*1024;
    const bool diag = (bj == bi);
    #pragma unroll
    for (int ct = 0; ct < 4; ++ct){
      bf16x8 b0 = *(const bf16x8*)&Ks[cur][(ct*16 + lq)*KST2 + lh*8];
      bf16x8 b1 = *(const bf16x8*)&Ks[cur][(ct*16 + lq)*KST2 + 32 + lh*8];
      f32x4 a = (f32x4){0.f,0.f,0.f,0.f};
      a = __builtin_amdgcn_mfma_f32_16x16x32_bf16(qf0, b0, a, 0, 0, 0);
      a = __builtin_amdgcn_mfma_f32_16x16x32_bf16(qf1, b1, a, 0, 0, 0);
      #pragma unroll
      for (int r = 0; r < 4; ++r){
        float e = __expf(a[r] * SCALEF);
        unsigned short eb = f2bf_trunc(e);
        int rrow = lh*4 + r, col = ct*16 + lq;
        Es[w][rrow*EST + col] = eb;
        float ev = bf2f(eb);
        int grow = w*16 + rrow;
        if (!diag || col < grow) dacc[r] += ev;
        if (diag && col == grow) dsh[w][rrow] = ev;
      }
    }
    #pragma unroll
    for (int it = 0; it < 2; ++it){
      int row = it*8 + (l >> 3), eo = (l & 7)*8;
      *(int4*)(Et + row*64 + eo) = *(const int4*)&Es[w][row*EST + eo];
    }
    if (bj < bi){
      *(int4*)&Ks[cur^1][srow*KST2 + sc]     = nk0;
      *(int4*)&Ks[cur^1][srow*KST2 + sc + 8] = nk1;
    }
    __syncthreads();
  }
  #pragma unroll
  for (int r = 0; r < 4; ++r){
    float d = dacc[r];
    #pragma unroll
    for (int mm = 1; mm < 16; mm <<= 1) d += __shfl_xor(d, mm);
    float dE = dsh[w][lh*4 + r];
    float den = fmaf(EPSF, d + dE, d);
    float rv = 1.0f / den;
    if (lq == 0)
      rinvg[(size_t)bh*S_ + bi*64 + w*16 + lh*4 + r] = rv;
  }
}

// ---------------- 4b: striped recurrence with urgent/deferred pipeline.
// (unchanged from R12/R13 — known-good at 87 µs)
__global__ __launch_bounds__(512)
__attribute__((amdgpu_waves_per_eu(2, 2)))
void k_recur3(const unsigned short* __restrict__ Eg,
              const float* __restrict__ rinvg,
              float* __restrict__ c_c,
              float* __restrict__ c_g){
  __shared__ float Pa[512];
  __shared__ float rso[512];
  __shared__ float csl[2][64];
  const int bh = blockIdx.x & 31, s = blockIdx.x >> 5;
  const unsigned short* Eh = Eg + (size_t)bh * 528 * 4096;
  const int tid = threadIdx.x, w = tid >> 6, l = tid & 63;
  const int lq = l & 15, lh = l >> 4;

  Pa[tid] = 0.f;
  rso[tid] = rinvg[(size_t)bh*S_ + (s + 4*w)*64 + l];
  __syncthreads();

  bf16x8 er[8];
  if (w == 0){
    const unsigned short* dt = Eh + ((size_t)(s*(s+1)/2) + s)*4096 + l*64;
    #pragma unroll
    for (int eb = 0; eb < 8; ++eb) er[eb] = *(const bf16x8*)(dt + eb*8);
  }

  bf16x8 dA0[5], dA1[5], dB0[5], dB1[5];
  bf16x8 ug0, ug1;
  const int lastc = s + 28;

  auto load_def = [&](int BJ, bf16x8 (&D0)[5], bf16x8 (&D1)[5]){
    int o0 = (BJ >= s) ? (((BJ - s) >> 2) + 1) : 0;
    int ex = (((BJ + 1) & 3) == s) ? 1 : 0;
    int nd = (8 - o0 - ex) * 4;
    if (w >= 1){
      #pragma unroll
      for (int k = 0; k < 5; ++k){
        int t = (w - 1) + k*7;
        if (t < nd){
          int ob = o0 + ex + (t >> 2);
          int bi = s + 4*ob;
          const unsigned short* tp =
              Eh + ((size_t)(bi*(bi+1)/2) + BJ)*4096 + (size_t)(t & 3)*1024;
          D0[k] = *(const bf16x8*)(tp + lq*64 + lh*8);
          D1[k] = *(const bf16x8*)(tp + lq*64 + 32 + lh*8);
        }
      }
      if (ex && w <= 4){
        int bi = BJ + 1;
        const unsigned short* tp =
            Eh + ((size_t)(bi*(bi+1)/2) + BJ)*4096 + (size_t)(w-1)*1024;
        ug0 = *(const bf16x8*)(tp + lq*64 + lh*8);
        ug1 = *(const bf16x8*)(tp + lq*64 + 32 + lh*8);
      }
    }
  };

  auto fold_def = [&](int BJP, bf16x8 (&D0)[5], bf16x8 (&D1)[5], int buf){
    int o0 = (BJP >= s) ? (((BJP - s) >> 2) + 1) : 0;
    int ex = (((BJP + 1) & 3) == s) ? 1 : 0;
    int nd = (8 - o0 - ex) * 4;
    if (w >= 1 && nd > 0){
      bf16x8 dc0 = (bf16x8){0,0,0,0,0,0,0,0};
      bf16x8 dc1 = (bf16x8){0,0,0,0,0,0,0,0};
      if (lq == 0){
        #pragma unroll
        for (int e = 0; e < 8; ++e){
          dc0[e] = (short)f2bf(csl[buf][lh*8 + e]);
          dc1[e] = (short)f2bf(csl[buf][32 + lh*8 + e]);
        }
      }
      #pragma unroll
      for (int k = 0; k < 5; ++k){
        int t = (w - 1) + k*7;
        if (t < nd){
          f32x4 o = (f32x4){0.f,0.f,0.f,0.f};
          o = __builtin_amdgcn_mfma_f32_16x16x32_bf16(D0[k], dc0, o, 0, 0, 0);
          o = __builtin_amdgcn_mfma_f32_16x16x32_bf16(D1[k], dc1, o, 0, 0, 0);
          if (lq == 0){
            int ob = o0 + ex + (t >> 2);
            float* base = Pa + ob*64 + (t & 3)*16 + lh*4;
            float4 v = *(float4*)base;
            v.x += o[0]; v.y += o[1]; v.z += o[2]; v.w += o[3];
            *(float4*)base = v;
          }
        }
      }
    }
  };

  auto iter = [&](int BJ, bf16x8 (&DL0)[5], bf16x8 (&DL1)[5],
                          bf16x8 (&DF0)[5], bf16x8 (&DF1)[5]){
    const int cur = BJ & 1;
    load_def(BJ, DL0, DL1);
    const int ex = (((BJ + 1) & 3) == s) ? 1 : 0;
    if (w == 0){
      if ((BJ & 3) == s){
        const int rr = l;
        const int o = (BJ - s) >> 2;
        float rinv = rso[o*64 + rr];
        float Pl = Pa[o*64 + rr];
        float cval = 0.f;
        #pragma unroll
        for (int eb = 0; eb < 8; ++eb){
          #pragma unroll
          for (int e = 0; e < 8; ++e){
            int r = eb*8 + e;
            float t2 = Pl * rinv;
            float cr = __uint_as_float(
                (unsigned)__builtin_amdgcn_readlane(__float_as_uint(t2), r));
            if (BJ == 0 && r == 0) cr = 1.0f;
            if (rr == r) cval = cr;
            float m = (rr > r) ? bf2f((unsigned short)er[eb][e]) : 0.f;
            Pl = fmaf(m, cr, Pl);
          }
        }
        csl[cur][rr] = cval;
        __hip_atomic_store((unsigned*)(c_c + (size_t)bh*S_ + BJ*64 + rr),
                           __float_as_uint(cval),
                           __ATOMIC_RELAXED, __HIP_MEMORY_SCOPE_AGENT);
        c_g[((size_t)(bh >> 4)*S_ + (BJ*64 + rr))*16 + (bh & 15)] = cval;
        int bn = BJ + 4;
        if (bn <= lastc){
          const unsigned short* dt =
              Eh + ((size_t)(bn*(bn+1)/2) + bn)*4096 + l*64;
          #pragma unroll
          for (int eb = 0; eb < 8; ++eb) er[eb] = *(const bf16x8*)(dt + eb*8);
        }
      } else {
        const unsigned* pp = (const unsigned*)(c_c + (size_t)bh*S_ + BJ*64 + l);
        unsigned v = __hip_atomic_load(pp, __ATOMIC_RELAXED,
                                       __HIP_MEMORY_SCOPE_AGENT);
        while (!__all(v != 0u)){
          __builtin_amdgcn_s_sleep(2);
          v = __hip_atomic_load(pp, __ATOMIC_RELAXED,
                                __HIP_MEMORY_SCOPE_AGENT);
        }
        csl[cur][l] = __uint_as_float(v);
      }
    } else if (BJ >= 1){
      fold_def(BJ - 1, DF0, DF1, cur ^ 1);
    }
    __syncthreads();
    if (ex && w >= 1 && w <= 4){
      bf16x8 uc0 = (bf16x8){0,0,0,0,0,0,0,0};
      bf16x8 uc1 = (bf16x8){0,0,0,0,0,0,0,0};
      if (lq == 0){
        #pragma unroll
        for (int e = 0; e < 8; ++e){
          uc0[e] = (short)f2bf(csl[cur][lh*8 + e]);
          uc1[e] = (short)f2bf(csl[cur][32 + lh*8 + e]);
        }
      }
      f32x4 o = (f32x4){0.f,0.f,0.f,0.f};
      o = __builtin_amdgcn_mfma_f32_16x16x32_bf16(ug0, uc0, o, 0, 0, 0);
      o = __builtin_amdgcn_mfma_f32_16x16x32_bf16(ug1, uc1, o, 0, 0, 0);
      if (lq == 0){
        int ou = (BJ + 1 - s) >> 2;
        float* base = Pa + ou*64 + (w-1)*16 + lh*4;
        float4 v = *(float4*)base;
        v.x += o[0]; v.y += o[1]; v.z += o[2]; v.w += o[3];
        *(float4*)base = v;
      }
    }
    __syncthreads();
  };

  for (int bj = 0; bj <= lastc; bj += 2){
    iter(bj,     dA0, dA1, dB0, dB1);
    if (bj + 1 <= lastc)
      iter(bj+1, dB0, dB1, dA0, dA1);
  }
}

// ---------------- 5: out[b,s,n] = bd[n] + sum_h c[b,s,h] * U[b,h,n]
__global__ void k_out(const float* __restrict__ c_g, const float* __restrict__ U,
                      const float* __restrict__ bd, float* __restrict__ out){
  int bs = blockIdx.x; int b = bs >> 11;
  __shared__ float ch[16];
  if (threadIdx.x < 16) ch[threadIdx.x] = c_g[(size_t)bs*16 + threadIdx.x];
  __syncthreads();
  int n = threadIdx.x * 4;
  float4 acc = *(const float4*)(bd + n);
  #pragma unroll
  for (int h = 0; h < 16; ++h){
    float cc = ch[h];
    float4 u = *(const float4*)(U + ((size_t)(b*16 + h))*1024 + n);
    acc.x = fmaf(cc, u.x, acc.x); acc.y = fmaf(cc, u.y, acc.y);
    acc.z = fmaf(cc, u.z, acc.z); acc.w = fmaf(cc, u.w, acc.w);
  }
  *(float4*)(out + (size_t)bs*1024 + n) = acc;
}

extern "C" void kernel_launch(void* const* d_in, const int* in_sizes, int n_in,
                              void* d_out, int out_size, void* d_ws, size_t ws_size,
                              hipStream_t stream) {
  const float* hs   = (const float*)d_in[0];   // [2][2048][1024]
  const int*   pos  = (const int*)d_in[1];     // [2048]
  const float* Wqkv = (const float*)d_in[2];   // [1024][3072]
  const float* bqkv = (const float*)d_in[3];   // [3072]
  const float* Wd   = (const float*)d_in[4];   // [1024][1024]
  const float* bd   = (const float*)d_in[5];   // [1024]
  float* out = (float*)d_out;

  // workspace layout
  char* ws = (char*)d_ws;
  unsigned short* Ab = (unsigned short*)(ws);                       // 8 MB
  unsigned short* WT = (unsigned short*)(ws + (8u<<20));            // 4 MB
  unsigned short* Qb = (unsigned short*)(ws + (12u<<20));           // 8 MB
  unsigned short* Kb = (unsigned short*)(ws + (20u<<20));           // 8 MB
  float* c_g  = (float*)(ws + (28u<<20) + 0x10000);                 // 256 KB
  float* U    = (float*)(ws + (28u<<20) + 0x50000);                 // 128 KB
  float* rinvg= (float*)(ws + (28u<<20) + 0x80000);                 // 256 KB
  float* c_c  = (float*)(ws + (28u<<20) + 0xC0000);                 // 256 KB
  unsigned short* Eg = (unsigned short*)(ws + (29u<<20));           // 132 MB

  k_prep   <<<6176, 256, 0, stream>>>(hs, Wqkv, bqkv, Wd, Ab, WT, U);
  k_gemm_qk<<<dim3(16, 32), 256, 0, stream>>>(Ab, WT, bqkv, pos, Qb, Kb);
  k_scores <<<1024, 256, 0, stream>>>(Qb, Kb, Eg, rinvg);
  hipMemsetAsync(c_c, 0, 32 * S_ * sizeof(float), stream);
  k_recur3 <<<128, 512, 0, stream>>>(Eg, rinvg, c_c, c_g);
  k_out    <<<4096, 256, 0, stream>>>(c_g, U, bd, out);
}